// Round 10
// baseline (319.677 us; speedup 1.0000x reference)
//
#include <hip/hip_runtime.h>

typedef unsigned short u16;
typedef u16 u16x4 __attribute__((ext_vector_type(4)));
typedef u16 u16x8 __attribute__((ext_vector_type(8)));
typedef __bf16 bf16;
typedef bf16 bf16x8 __attribute__((ext_vector_type(8)));
typedef float f32x4 __attribute__((ext_vector_type(4)));

__device__ __forceinline__ float bf2f(u16 v) {
  union { unsigned u; float f; } x; x.u = ((unsigned)v) << 16; return x.f;
}
__device__ __forceinline__ u16 f2bf(float f) {
  union { float f; unsigned u; } x; x.f = f;
  unsigned u = x.u;
  u += 0x7fffu + ((u >> 16) & 1u);   // RNE
  return (u16)(u >> 16);
}
// hw packed f32->bf16 (RNE), 2 values / instr (no builtin on gfx950, m240)
__device__ __forceinline__ unsigned cvt2bf(float lo, float hi) {
  unsigned r;
  asm("v_cvt_pk_bf16_f32 %0, %1, %2" : "=v"(r) : "v"(lo), "v"(hi));
  return r;
}

// lgkm-only barrier: LDS drained, global loads stay in flight
__device__ __forceinline__ void bar_lgkm() {
  asm volatile("s_waitcnt lgkmcnt(0)" ::: "memory");
  __builtin_amdgcn_s_barrier();
}

// async global->LDS, 16B per lane; LDS base wave-uniform, global source per-lane (m173)
#define GLDS16(g, l) __builtin_amdgcn_global_load_lds( \
    (const __attribute__((address_space(1))) unsigned int*)(const void*)(g), \
    (__attribute__((address_space(3))) unsigned int*)(void*)(l), 16, 0, 0)

// ---------------- fused prep + downsample (v4 merge: both prior causes fixed) ----------
// grid 7680, ds blocks 1-in-10 (R3's interleave, fixes R2's clumping).
// ds keeps the R1-proven 10KB structure (fixes R3's 50KB-LDS occupancy kill);
// W read fp32 DIRECT with fragment-side cvt_pk -> ds has no prep dependency.
// Uniform LDS = 10.2KB; streaming cvt blocks unhurt.
__global__ __launch_bounds__(256) void prepds_k(
    const float* __restrict__ Wq, const float* __restrict__ Wk,
    const float* __restrict__ Wv, const float* __restrict__ Wout,
    const float* __restrict__ query,
    const float* __restrict__ W_kds, const float* __restrict__ W_vds,
    const float* __restrict__ b0, const float* __restrict__ b1,
    const float* __restrict__ b2, const float* __restrict__ b3,
    const float* __restrict__ key, const float* __restrict__ value,
    u16* __restrict__ WT, u16* __restrict__ q_bf,
    u16* __restrict__ dstB, u16* __restrict__ key_ds)
{
  __shared__ char sm[10240];
  const int blk = blockIdx.x;
  const int t = threadIdx.x;

  if (blk % 10 == 0) {
    // ---- downsample (R1 structure + lgkm barrier + fp32-W fragments) ----
    u16* Bs = (u16*)sm;                      // [2][64*40]
    const int id = blk / 10;                 // [0,768)
    const int nt = (id % 12) * 64;
    const int yb = id / 12;
    const int pair = yb >> 5, b = yb & 31;
    const float* src = (pair ? value : key) + (size_t)b * 512 * 768;
    const float* W32 = pair ? W_vds : W_kds;  // fp32 [64][512]
    u16* dst = key_ds + (size_t)pair * 1572864 + (size_t)b * 49152;
    const int wave = t >> 6, lane = t & 63;
    const int wm = (wave >> 1) * 32, wn = (wave & 1) * 32;
    const int lrow = lane & 15, quad = lane >> 4;
    const int bn = t & 63, bk8 = (t >> 6) * 8;
    const float* bcol = src + nt + bn;

    auto ldW = [&](int row, int kq) -> bf16x8 {
      f32x4 w0 = *(const f32x4*)&W32[(size_t)row * 512 + kq];
      f32x4 w1 = *(const f32x4*)&W32[(size_t)row * 512 + kq + 4];
      union { unsigned u[4]; bf16x8 v; } cv;
      cv.u[0] = cvt2bf(w0[0], w0[1]); cv.u[1] = cvt2bf(w0[2], w0[3]);
      cv.u[2] = cvt2bf(w1[0], w1[1]); cv.u[3] = cvt2bf(w1[2], w1[3]);
      return cv.v;
    };

    f32x4 acc[2][2] = {};
    float breg[8];
    bf16x8 av[2][2];

    #pragma unroll
    for (int i = 0; i < 8; ++i) breg[i] = bcol[(size_t)(bk8 + i) * 768];
    #pragma unroll
    for (int i = 0; i < 2; ++i) av[0][i] = ldW(wm + i * 16 + lrow, quad * 8);

    #pragma unroll
    for (int step = 0; step < 16; ++step) {
      const int cur = step & 1, nxt = cur ^ 1;
      u16x8 wv;
      #pragma unroll
      for (int i = 0; i < 8; ++i) wv[i] = f2bf(breg[i]);
      *(u16x8*)&Bs[cur * 2560 + bn * 40 + bk8] = wv;
      if (step < 15) {
        const int k1 = (step + 1) * 32;
        #pragma unroll
        for (int i = 0; i < 8; ++i) breg[i] = bcol[(size_t)(k1 + bk8 + i) * 768];
        #pragma unroll
        for (int i = 0; i < 2; ++i) av[nxt][i] = ldW(wm + i * 16 + lrow, k1 + quad * 8);
      }
      bar_lgkm();   // global prefetch stays in flight; LDS writes visible
      bf16x8 bv[2];
      #pragma unroll
      for (int j = 0; j < 2; ++j)
        bv[j] = *(const bf16x8*)&Bs[cur * 2560 + (wn + j * 16 + lrow) * 40 + quad * 8];
      #pragma unroll
      for (int i = 0; i < 2; ++i)
        #pragma unroll
        for (int j = 0; j < 2; ++j)
          acc[i][j] = __builtin_amdgcn_mfma_f32_16x16x32_bf16(av[cur][i], bv[j], acc[i][j], 0, 0, 0);
    }

    #pragma unroll
    for (int i = 0; i < 2; ++i)
      #pragma unroll
      for (int j = 0; j < 2; ++j) {
        const int col = nt + wn + j * 16 + lrow;
        #pragma unroll
        for (int r = 0; r < 4; ++r) {
          const int row = wm + i * 16 + quad * 4 + r;
          dst[(size_t)row * 768 + col] = f2bf(acc[i][j][r]);
        }
      }
    return;
  }

  const int pid = blk - blk / 10 - 1;        // [0, 6912)
  if (pid < 576) {
    // ---- weight transpose ----
    u16 (*T)[72] = (u16(*)[72])sm;
    const int bz = pid / 144, rr = pid % 144;
    const int r0 = (rr / 12) * 64, c0 = (rr % 12) * 64;
    const float* W = (bz == 0) ? Wq : (bz == 1) ? Wk : (bz == 2) ? Wv : Wout;
    u16* O = WT + (size_t)bz * 768 * 768;
    #pragma unroll
    for (int p = 0; p < 2; ++p) {
      int v = t + p * 256;
      int r = v / 8, c = (v % 8) * 8;
      f32x4 x0 = *(const f32x4*)&W[(size_t)(r0 + r) * 768 + c0 + c];
      f32x4 x1 = *(const f32x4*)&W[(size_t)(r0 + r) * 768 + c0 + c + 4];
      #pragma unroll
      for (int i = 0; i < 4; ++i) { T[r][c + i] = f2bf(x0[i]); T[r][c + 4 + i] = f2bf(x1[i]); }
    }
    __syncthreads();
    #pragma unroll
    for (int p = 0; p < 2; ++p) {
      int v = t + p * 256;
      int r = v / 8, c = (v % 8) * 8;
      u16x8 tv;
      #pragma unroll
      for (int i = 0; i < 8; ++i) tv[i] = T[c + i][r];
      *(u16x8*)&O[(size_t)(c0 + r) * 768 + r0 + c] = tv;
    }
  } else if (pid < 6720) {
    // ---- query fp32 -> bf16 ----
    const size_t i = (size_t)(pid - 576) * 256 + t;   // 6144*256 slots, *8 = 12582912
    f32x4 a = *(const f32x4*)&query[i * 8];
    f32x4 b = *(const f32x4*)&query[i * 8 + 4];
    u16x8 w;
    #pragma unroll
    for (int j = 0; j < 4; ++j) { w[j] = f2bf(a[j]); w[4 + j] = f2bf(b[j]); }
    *(u16x8*)&q_bf[i * 8] = w;
  } else if (pid < 6732) {
    // ---- bias converts: 3072 elements ----
    const int i = (pid - 6720) * 256 + t;
    if (i < 3072) {
      int s = i / 768, si = i % 768;
      const float* src = (s == 0) ? b0 : (s == 1) ? b1 : (s == 2) ? b2 : b3;
      dstB[i] = f2bf(src[si]);
    }
  }
}

// ---------------- bf16 GEMM, BK=64, GLDS, swizzled, XCD-chunked (R6 proven) ----------
template<int ACT, bool OF32>
__global__ __launch_bounds__(256) void gemm64_k(
    const u16* __restrict__ A, int lda,
    const u16* __restrict__ Bt, int ldb,
    void* __restrict__ Craw, int ldc,
    const u16* __restrict__ bias, int K)
{
  __shared__ u16 As[128 * 64];   // 16KB, swizzled ch^(r&7)
  __shared__ u16 Bs[128 * 64];   // 16KB, swizzled
  const int blk = blockIdx.x;                   // 768 = 128 mt x 6 nt
  const int wg = (blk & 7) * 96 + (blk >> 3);
  const int mt = (wg / 6) * 128, nt = (wg % 6) * 128;
  const int t = threadIdx.x, wave = t >> 6, lane = t & 63;
  const int wm = (wave >> 1) * 64, wn = (wave & 1) * 64;
  const int lrow = lane & 15, quad = lane >> 4;
  f32x4 acc[4][4] = {};

  for (int k0 = 0; k0 < K; k0 += 64) {
    __syncthreads();
    #pragma unroll
    for (int p = 0; p < 4; ++p) {
      const int slot = wave * 256 + p * 64 + lane;
      const int r = slot >> 3, ch = slot & 7;
      const int chs = ch ^ (r & 7);
      const int lb = (wave * 256 + p * 64) * 8;
      GLDS16(&A[(size_t)(mt + r) * lda + k0 + chs * 8], &As[lb]);
      GLDS16(&Bt[(size_t)(nt + r) * ldb + k0 + chs * 8], &Bs[lb]);
    }
    __syncthreads();

    #pragma unroll
    for (int c = 0; c < 2; ++c) {
      bf16x8 av[4], bv[4];
      #pragma unroll
      for (int i = 0; i < 4; ++i) {
        const int row = wm + i * 16 + lrow;
        av[i] = *(const bf16x8*)&As[row * 64 + (((c * 4 + quad) ^ (row & 7)) * 8)];
      }
      #pragma unroll
      for (int j = 0; j < 4; ++j) {
        const int row = wn + j * 16 + lrow;
        bv[j] = *(const bf16x8*)&Bs[row * 64 + (((c * 4 + quad) ^ (row & 7)) * 8)];
      }
      #pragma unroll
      for (int i = 0; i < 4; ++i)
        #pragma unroll
        for (int j = 0; j < 4; ++j)
          acc[i][j] = __builtin_amdgcn_mfma_f32_16x16x32_bf16(av[i], bv[j], acc[i][j], 0, 0, 0);
    }
  }

  #pragma unroll
  for (int i = 0; i < 4; ++i) {
    #pragma unroll
    for (int j = 0; j < 4; ++j) {
      const int col = nt + wn + j * 16 + lrow;
      const float badd = bias ? bf2f(bias[col]) : 0.0f;
      #pragma unroll
      for (int r = 0; r < 4; ++r) {
        const int row = mt + wm + i * 16 + quad * 4 + r;
        float v = acc[i][j][r] + badd;
        if constexpr (ACT == 1) v = v > 0.0f ? v + 1.0f : __expf(v);
        if constexpr (OF32) ((float*)Craw)[(size_t)row * ldc + col] = v;
        else                ((u16*)Craw)[(size_t)row * ldc + col] = f2bf(v);
      }
    }
  }
}

// ---------------- fused phi_k/vals GEMM + KV-state (R8-exact, proven) ----------
__global__ __launch_bounds__(256) void fkv_k(
    const u16* __restrict__ key_ds,   // [2][32][64][768] bf16
    const u16* __restrict__ WT,       // WkT at +768^2, WvT at +2*768^2
    const u16* __restrict__ bias_c,   // bk at +768, bv at +1536
    u16* __restrict__ sT, float* __restrict__ z)
{
  __shared__ char sm[32768];
  u16* T0 = (u16*)sm;                 // 4 stage tiles [64][64] bf16, chunk-swizzled
  u16* Pt = (u16*)sm;                 // overlay after GEMM: [64][72]
  u16* Vt = (u16*)(sm + 9216);        // [64][72]
  const int x = blockIdx.x;           // b*12 + n
  const int b = x / 12, n = x % 12;
  const int t = threadIdx.x, wave = t >> 6, lane = t & 63;
  const u16* srcs[4] = {
    key_ds + (size_t)b * 49152,
    WT + 589824 + (size_t)n * 49152,
    key_ds + 1572864 + (size_t)b * 49152,
    WT + 2 * 589824 + (size_t)n * 49152 };
  const int grow = lane >> 3;
  const int gchunk = (lane & 7) ^ (grow & 7);
  const int isV = wave & 1;
  const int wm = (wave >> 1) * 32;
  u16* Atile = T0 + (isV ? 2 : 0) * 4096;
  u16* Btile = T0 + (isV ? 3 : 1) * 4096;
  const int lrow = lane & 15, quad = lane >> 4;
  f32x4 acc[2][4] = {};

  for (int k0 = 0; k0 < 768; k0 += 64) {
    const u16* s = srcs[wave];
    u16* dtile = T0 + wave * 4096;
    #pragma unroll
    for (int j = 0; j < 8; ++j) {
      const u16* gsrc = s + (size_t)(j * 8 + grow) * 768 + k0 + gchunk * 8;
      GLDS16(gsrc, (char*)dtile + j * 1024);
    }
    __syncthreads();
    #pragma unroll
    for (int c = 0; c < 2; ++c) {
      bf16x8 av[2], bv[4];
      #pragma unroll
      for (int i = 0; i < 2; ++i) {
        const int row = wm + i * 16 + lrow;
        av[i] = *(const bf16x8*)&Atile[row * 64 + (((c * 4 + quad) ^ (row & 7)) * 8)];
      }
      #pragma unroll
      for (int j = 0; j < 4; ++j) {
        const int row = j * 16 + lrow;
        bv[j] = *(const bf16x8*)&Btile[row * 64 + (((c * 4 + quad) ^ (row & 7)) * 8)];
      }
      #pragma unroll
      for (int i = 0; i < 2; ++i)
        #pragma unroll
        for (int j = 0; j < 4; ++j)
          acc[i][j] = __builtin_amdgcn_mfma_f32_16x16x32_bf16(av[i], bv[j], acc[i][j], 0, 0, 0);
    }
    __syncthreads();
  }

  const u16* bias = bias_c + (isV ? 1536 : 768) + n * 64;
  u16* Ttile = isV ? Vt : Pt;
  #pragma unroll
  for (int i = 0; i < 2; ++i)
    #pragma unroll
    for (int j = 0; j < 4; ++j) {
      const int col = j * 16 + lrow;
      const float badd = bf2f(bias[col]);
      u16x4 pk4;
      #pragma unroll
      for (int r = 0; r < 4; ++r) {
        float v = acc[i][j][r] + badd;
        if (!isV) v = v > 0.0f ? v + 1.0f : __expf(v);
        pk4[r] = f2bf(v);
      }
      *(u16x4*)&Ttile[col * 72 + wm + i * 16 + quad * 4] = pk4;
    }
  __syncthreads();

  const int wm2 = (wave >> 1) * 32, wn2 = (wave & 1) * 32;
  f32x4 a2[2][2] = {};
  #pragma unroll
  for (int c = 0; c < 2; ++c) {
    bf16x8 av[2], bv[2];
    #pragma unroll
    for (int i = 0; i < 2; ++i)
      av[i] = *(const bf16x8*)&Vt[(wm2 + i * 16 + lrow) * 72 + c * 32 + quad * 8];
    #pragma unroll
    for (int j = 0; j < 2; ++j)
      bv[j] = *(const bf16x8*)&Pt[(wn2 + j * 16 + lrow) * 72 + c * 32 + quad * 8];
    #pragma unroll
    for (int i = 0; i < 2; ++i)
      #pragma unroll
      for (int j = 0; j < 2; ++j)
        a2[i][j] = __builtin_amdgcn_mfma_f32_16x16x32_bf16(av[i], bv[j], a2[i][j], 0, 0, 0);
  }
  u16* sTg = sT + (size_t)x * 4096;
  #pragma unroll
  for (int i = 0; i < 2; ++i)
    #pragma unroll
    for (int j = 0; j < 2; ++j)
      #pragma unroll
      for (int r = 0; r < 4; ++r)
        sTg[(size_t)(wm2 + i * 16 + quad * 4 + r) * 64 + wn2 + j * 16 + lrow] = f2bf(a2[i][j][r]);
  if (t < 64) {
    float zz = 0.f;
    #pragma unroll
    for (int g = 0; g < 8; ++g) {
      u16x8 p = *(const u16x8*)&Pt[t * 72 + g * 8];
      #pragma unroll
      for (int e = 0; e < 8; ++e) zz += bf2f(p[e]);
    }
    z[(size_t)x * 64 + t] = zz;
  }
}

// ---------------- a_v = (phi_q @ s) / (phi_q . z + eps), fused qz, in-place (R6) --------
__global__ __launch_bounds__(256) void attn_av_k(
    u16* __restrict__ phi_q, const u16* __restrict__ sT, const float* __restrict__ zbuf)
{
  __shared__ u16 As[64 * 72];
  __shared__ u16 Bs[64 * 72];
  __shared__ float zv[64];
  __shared__ float zpart[4][64];
  __shared__ float zq[64];
  const int x = blockIdx.x, y = blockIdx.y;
  const int b = y / 12, n = y % 12;
  const int t = threadIdx.x;
  u16* Abase = phi_q + (size_t)b * 512 * 768 + (size_t)x * 64 * 768 + n * 64;
  const u16* Bbase = sT + (size_t)y * 4096;
  if (t < 64) zv[t] = zbuf[(size_t)y * 64 + t];
  #pragma unroll
  for (int p = 0; p < 2; ++p) {
    int v = t + p * 256;
    int r = v >> 3, c = (v & 7) * 8;
    *(u16x8*)&As[r * 72 + c] = *(const u16x8*)&Abase[(size_t)r * 768 + c];
    *(u16x8*)&Bs[r * 72 + c] = *(const u16x8*)&Bbase[r * 64 + c];
  }
  __syncthreads();
  {
    int r = t & 63, seg = t >> 6;
    float s = 0.f;
    #pragma unroll
    for (int j = 0; j < 16; ++j) s += bf2f(As[r * 72 + seg * 16 + j]) * zv[seg * 16 + j];
    zpart[seg][r] = s;
  }
  __syncthreads();
  if (t < 64) {
    float s = zpart[0][t] + zpart[1][t] + zpart[2][t] + zpart[3][t];
    zq[t] = 1.0f / (s + 1e-6f);
  }
  const int wave = t >> 6, lane = t & 63;
  const int wm = (wave >> 1) * 32, wn = (wave & 1) * 32;
  const int lrow = lane & 15, quad = lane >> 4;
  f32x4 acc[2][2] = {};
  #pragma unroll
  for (int c = 0; c < 2; ++c) {
    bf16x8 av[2], bv[2];
    #pragma unroll
    for (int i = 0; i < 2; ++i) av[i] = *(const bf16x8*)&As[(wm + i * 16 + lrow) * 72 + c * 32 + quad * 8];
    #pragma unroll
    for (int j = 0; j < 2; ++j) bv[j] = *(const bf16x8*)&Bs[(wn + j * 16 + lrow) * 72 + c * 32 + quad * 8];
    #pragma unroll
    for (int i = 0; i < 2; ++i)
      #pragma unroll
      for (int j = 0; j < 2; ++j)
        acc[i][j] = __builtin_amdgcn_mfma_f32_16x16x32_bf16(av[i], bv[j], acc[i][j], 0, 0, 0);
  }
  __syncthreads();
  #pragma unroll
  for (int i = 0; i < 2; ++i)
    #pragma unroll
    for (int j = 0; j < 2; ++j) {
      const int col = wn + j * 16 + lrow;
      #pragma unroll
      for (int r = 0; r < 4; ++r) {
        const int row = wm + i * 16 + quad * 4 + r;
        Abase[(size_t)row * 768 + col] = f2bf(acc[i][j][r] * zq[row]);
      }
    }
}

__global__ void tagfill_k(float* out, float val, int n) {
  int i = blockIdx.x * 256 + threadIdx.x;
  if (i < n) out[i] = val;
}

extern "C" void kernel_launch(void* const* d_in, const int* in_sizes, int n_in,
                              void* d_out, int out_size, void* d_ws, size_t ws_size,
                              hipStream_t stream) {
  (void)out_size;
  float* out = (float*)d_out;

  int o;
  if (n_in >= 14 && in_sizes[3] == 1) o = 4;
  else if (n_in == 13) o = 3;
  else { tagfill_k<<<4, 256, 0, stream>>>(out, 77.0f, 1024); return; }
  if (in_sizes[0] != 12582912 || in_sizes[o + 0] != 32768 || in_sizes[o + 2] != 589824) {
    tagfill_k<<<4, 256, 0, stream>>>(out, 88.0f, 1024); return;
  }

  const float* query = (const float*)d_in[0];
  const float* key   = (const float*)d_in[1];
  const float* value = (const float*)d_in[2];
  const float* W_kds = (const float*)d_in[o + 0];
  const float* W_vds = (const float*)d_in[o + 1];
  const float* Wq   = (const float*)d_in[o + 2];
  const float* bq   = (const float*)d_in[o + 3];
  const float* Wk   = (const float*)d_in[o + 4];
  const float* bk   = (const float*)d_in[o + 5];
  const float* Wv   = (const float*)d_in[o + 6];
  const float* bv   = (const float*)d_in[o + 7];
  const float* Wout = (const float*)d_in[o + 8];
  const float* bout = (const float*)d_in[o + 9];

  const size_t NEED = 61478912;
  if (ws_size < NEED) { tagfill_k<<<4, 256, 0, stream>>>(out, 123.0f, 1024); return; }

  char* base = (char*)d_ws;
  u16*   WT     = (u16*)base;                         // 4,718,592
  char*  Breg   = base + 4718592;                     // 25,165,824 region
  u16*   q_bf   = (u16*)Breg;                         // dies after phi_q GEMM
  u16*   sT     = (u16*)Breg;                         // then sT (over dead q_bf)
  float* zbuf   = (float*)(Breg + 3145728);
  u16*   phi_q  = (u16*)(base + 29884416);            // 25,165,824
  u16*   bias_c = (u16*)(base + 55181312);            // 6,144
  u16*   key_ds = (u16*)(base + 55187456);            // 6,291,456
  u16* a_v = phi_q;
  u16* WqT   = WT;
  u16* WoutT = WT + 3 * 768 * 768;
  u16* bq_c = bias_c, *bout_c = bias_c + 2304;

  // 1. fused prep + downsample (ds 1-in-10, fp32-W fragments, 10KB uniform LDS)
  prepds_k<<<7680, 256, 0, stream>>>(Wq, Wk, Wv, Wout, query, W_kds, W_vds,
                                     bq, bk, bv, bout, key, value,
                                     WT, q_bf, bias_c, key_ds);

  // 2. phi_q = elu(q_bf @ WqT + bq) + 1  (bf16 A, GLDS, BK=64)
  gemm64_k<1, false><<<768, 256, 0, stream>>>(
      q_bf, 768, WqT, 768, phi_q, 768, bq_c, 768);

  // 3. fused phi_k/vals + KV state (R8-exact; sT/zbuf overwrite dead q_bf)
  fkv_k<<<384, 256, 0, stream>>>(key_ds, WT, bias_c, sT, zbuf);

  // 4. a_v = (phi_q @ s) * 1/(phi_q.z+eps), fused qz, in-place
  attn_av_k<<<dim3(8, 384), 256, 0, stream>>>(phi_q, sT, zbuf);

  // 5. out = a_v @ Wout + bout (fp32 C, XCD-swizzled)
  gemm64_k<0, true><<<768, 256, 0, stream>>>(
      a_v, 768, WoutT, 768, out, 768, bout_c, 768);
}

// Round 11
// 298.872 us; speedup vs baseline: 1.0696x; 1.0696x over previous
//
#include <hip/hip_runtime.h>

typedef unsigned short u16;
typedef u16 u16x4 __attribute__((ext_vector_type(4)));
typedef u16 u16x8 __attribute__((ext_vector_type(8)));
typedef __bf16 bf16;
typedef bf16 bf16x8 __attribute__((ext_vector_type(8)));
typedef float f32x4 __attribute__((ext_vector_type(4)));

__device__ __forceinline__ float bf2f(u16 v) {
  union { unsigned u; float f; } x; x.u = ((unsigned)v) << 16; return x.f;
}
__device__ __forceinline__ u16 f2bf(float f) {
  union { float f; unsigned u; } x; x.f = f;
  unsigned u = x.u;
  u += 0x7fffu + ((u >> 16) & 1u);   // RNE
  return (u16)(u >> 16);
}

// lgkm-only barrier: LDS drained, global loads stay in flight
__device__ __forceinline__ void bar_lgkm() {
  asm volatile("s_waitcnt lgkmcnt(0)" ::: "memory");
  __builtin_amdgcn_s_barrier();
}

// async global->LDS, 16B per lane; LDS base wave-uniform, global source per-lane (m173)
#define GLDS16(g, l) __builtin_amdgcn_global_load_lds( \
    (const __attribute__((address_space(1))) unsigned int*)(const void*)(g), \
    (__attribute__((address_space(3))) unsigned int*)(void*)(l), 16, 0, 0)

// ---------------- prep: 4 weight transposes + query cvt + small cvts (R0/R8 proven) -----
// grid 6988: [0,576) transpose4; [576,6720) query fp32->bf16; [6720,6988) small converts
__global__ __launch_bounds__(256) void prep_k(
    const float* __restrict__ Wq, const float* __restrict__ Wk,
    const float* __restrict__ Wv, const float* __restrict__ Wout,
    const float* __restrict__ query,
    const float* __restrict__ wkds, const float* __restrict__ wvds,
    const float* __restrict__ b0, const float* __restrict__ b1,
    const float* __restrict__ b2, const float* __restrict__ b3,
    u16* __restrict__ WT, u16* __restrict__ q_bf,
    u16* __restrict__ dstW, u16* __restrict__ dstB)
{
  __shared__ u16 T[64][72];
  const int blk = blockIdx.x;
  const int t = threadIdx.x;
  if (blk < 576) {
    const int bz = blk / 144, rr = blk % 144;
    const int r0 = (rr / 12) * 64, c0 = (rr % 12) * 64;
    const float* W = (bz == 0) ? Wq : (bz == 1) ? Wk : (bz == 2) ? Wv : Wout;
    u16* O = WT + (size_t)bz * 768 * 768;
    #pragma unroll
    for (int p = 0; p < 2; ++p) {
      int v = t + p * 256;
      int r = v / 8, c = (v % 8) * 8;
      f32x4 x0 = *(const f32x4*)&W[(size_t)(r0 + r) * 768 + c0 + c];
      f32x4 x1 = *(const f32x4*)&W[(size_t)(r0 + r) * 768 + c0 + c + 4];
      #pragma unroll
      for (int i = 0; i < 4; ++i) { T[r][c + i] = f2bf(x0[i]); T[r][c + 4 + i] = f2bf(x1[i]); }
    }
    __syncthreads();
    #pragma unroll
    for (int p = 0; p < 2; ++p) {
      int v = t + p * 256;
      int r = v / 8, c = (v % 8) * 8;
      u16x8 tv;
      #pragma unroll
      for (int i = 0; i < 8; ++i) tv[i] = T[c + i][r];
      *(u16x8*)&O[(size_t)(c0 + r) * 768 + r0 + c] = tv;
    }
  } else if (blk < 6720) {
    const size_t i = (size_t)(blk - 576) * 256 + t;   // 6144*256 slots, *8 = 12582912
    f32x4 a = *(const f32x4*)&query[i * 8];
    f32x4 b = *(const f32x4*)&query[i * 8 + 4];
    u16x8 w;
    #pragma unroll
    for (int j = 0; j < 4; ++j) { w[j] = f2bf(a[j]); w[4 + j] = f2bf(b[j]); }
    *(u16x8*)&q_bf[i * 8] = w;
  } else {
    const int i = (blk - 6720) * 256 + t;   // 268*256 = 68608 = 65536 + 3072
    if (i < 32768)      dstW[i] = f2bf(wkds[i]);
    else if (i < 65536) dstW[i] = f2bf(wvds[i - 32768]);
    else {
      int j = i - 65536, s = j / 768, si = j % 768;
      const float* src = (s == 0) ? b0 : (s == 1) ? b1 : (s == 2) ? b2 : b3;
      dstB[j] = f2bf(src[si]);
    }
  }
}

// ---------------- downsample v5: R1 structure, N-tile 32 -> 1536 blocks (6/CU) ----------
// ds was grid-limited: 768 blocks = 3/CU cap, occupancy 24%, nothing hides the 16-step
// latency chain. N=32: 2x blocks co-resident (6/CU), 4 loads/thread/step (was 8).
// Same HBM traffic (columns partition; W L2-hot). 4 waves x 16 output rows.
__global__ __launch_bounds__(256) void ds_k(
    const u16* __restrict__ Wds,      // bf16 [2][64][512]
    const float* __restrict__ key, const float* __restrict__ value,
    u16* __restrict__ key_ds)         // [2][32][64][768] (key_ds ++ val_ds contiguous)
{
  __shared__ u16 Bs[2][32 * 40];     // 5KB, [buf][n][k] stride 40
  const int pair = blockIdx.y >> 5, b = blockIdx.y & 31;
  const float* src = (pair ? value : key) + (size_t)b * 512 * 768;
  const u16* W = Wds + pair * 32768;
  u16* dst = key_ds + (size_t)pair * 1572864 + (size_t)b * 49152;
  const int nt = blockIdx.x * 32;
  const int t = threadIdx.x, wave = t >> 6, lane = t & 63;
  const int wm = wave * 16;                    // 4 waves x 16 kds-rows
  const int lrow = lane & 15, quad = lane >> 4;
  const int bn = t & 31, bk4 = (t >> 5) * 4;   // owned column, 4-row k-group
  const float* bcol = src + nt + bn;

  f32x4 acc[2] = {};
  float breg[4];
  bf16x8 av[2];

  #pragma unroll
  for (int i = 0; i < 4; ++i) breg[i] = bcol[(size_t)(bk4 + i) * 768];
  av[0] = *(const bf16x8*)&W[(size_t)(wm + lrow) * 512 + quad * 8];

  #pragma unroll
  for (int step = 0; step < 16; ++step) {
    const int cur = step & 1, nxt = cur ^ 1;
    u16x4 wv;
    #pragma unroll
    for (int i = 0; i < 4; ++i) wv[i] = f2bf(breg[i]);
    *(u16x4*)&Bs[cur][bn * 40 + bk4] = wv;
    if (step < 15) {
      const int k1 = (step + 1) * 32;
      #pragma unroll
      for (int i = 0; i < 4; ++i) breg[i] = bcol[(size_t)(k1 + bk4 + i) * 768];
      av[nxt] = *(const bf16x8*)&W[(size_t)(wm + lrow) * 512 + k1 + quad * 8];
    }
    bar_lgkm();   // LDS writes visible; global prefetch stays in flight
    bf16x8 bv[2];
    #pragma unroll
    for (int j = 0; j < 2; ++j)
      bv[j] = *(const bf16x8*)&Bs[cur][(j * 16 + lrow) * 40 + quad * 8];
    #pragma unroll
    for (int j = 0; j < 2; ++j)
      acc[j] = __builtin_amdgcn_mfma_f32_16x16x32_bf16(av[cur], bv[j], acc[j], 0, 0, 0);
    // read(step,buf) vs write(step+2,buf) separated by step+1's barrier: dbuf safe
  }

  #pragma unroll
  for (int j = 0; j < 2; ++j) {
    const int col = nt + j * 16 + lrow;
    #pragma unroll
    for (int r = 0; r < 4; ++r) {
      const int row = wm + quad * 4 + r;
      dst[(size_t)row * 768 + col] = f2bf(acc[j][r]);
    }
  }
}

// ---------------- bf16 GEMM, BK=64, GLDS, swizzled, XCD-chunked (R6 proven) ----------
template<int ACT, bool OF32>
__global__ __launch_bounds__(256) void gemm64_k(
    const u16* __restrict__ A, int lda,
    const u16* __restrict__ Bt, int ldb,
    void* __restrict__ Craw, int ldc,
    const u16* __restrict__ bias, int K)
{
  __shared__ u16 As[128 * 64];   // 16KB, swizzled ch^(r&7)
  __shared__ u16 Bs[128 * 64];   // 16KB, swizzled
  const int blk = blockIdx.x;                   // 768 = 128 mt x 6 nt
  const int wg = (blk & 7) * 96 + (blk >> 3);
  const int mt = (wg / 6) * 128, nt = (wg % 6) * 128;
  const int t = threadIdx.x, wave = t >> 6, lane = t & 63;
  const int wm = (wave >> 1) * 64, wn = (wave & 1) * 64;
  const int lrow = lane & 15, quad = lane >> 4;
  f32x4 acc[4][4] = {};

  for (int k0 = 0; k0 < K; k0 += 64) {
    __syncthreads();
    #pragma unroll
    for (int p = 0; p < 4; ++p) {
      const int slot = wave * 256 + p * 64 + lane;
      const int r = slot >> 3, ch = slot & 7;
      const int chs = ch ^ (r & 7);
      const int lb = (wave * 256 + p * 64) * 8;
      GLDS16(&A[(size_t)(mt + r) * lda + k0 + chs * 8], &As[lb]);
      GLDS16(&Bt[(size_t)(nt + r) * ldb + k0 + chs * 8], &Bs[lb]);
    }
    __syncthreads();

    #pragma unroll
    for (int c = 0; c < 2; ++c) {
      bf16x8 av[4], bv[4];
      #pragma unroll
      for (int i = 0; i < 4; ++i) {
        const int row = wm + i * 16 + lrow;
        av[i] = *(const bf16x8*)&As[row * 64 + (((c * 4 + quad) ^ (row & 7)) * 8)];
      }
      #pragma unroll
      for (int j = 0; j < 4; ++j) {
        const int row = wn + j * 16 + lrow;
        bv[j] = *(const bf16x8*)&Bs[row * 64 + (((c * 4 + quad) ^ (row & 7)) * 8)];
      }
      #pragma unroll
      for (int i = 0; i < 4; ++i)
        #pragma unroll
        for (int j = 0; j < 4; ++j)
          acc[i][j] = __builtin_amdgcn_mfma_f32_16x16x32_bf16(av[i], bv[j], acc[i][j], 0, 0, 0);
    }
  }

  #pragma unroll
  for (int i = 0; i < 4; ++i) {
    #pragma unroll
    for (int j = 0; j < 4; ++j) {
      const int col = nt + wn + j * 16 + lrow;
      const float badd = bias ? bf2f(bias[col]) : 0.0f;
      #pragma unroll
      for (int r = 0; r < 4; ++r) {
        const int row = mt + wm + i * 16 + quad * 4 + r;
        float v = acc[i][j][r] + badd;
        if constexpr (ACT == 1) v = v > 0.0f ? v + 1.0f : __expf(v);
        if constexpr (OF32) ((float*)Craw)[(size_t)row * ldc + col] = v;
        else                ((u16*)Craw)[(size_t)row * ldc + col] = f2bf(v);
      }
    }
  }
}

// ---------------- fused phi_k/vals GEMM + KV-state (R8-exact, proven) ----------
__global__ __launch_bounds__(256) void fkv_k(
    const u16* __restrict__ key_ds,   // [2][32][64][768] bf16
    const u16* __restrict__ WT,       // WkT at +768^2, WvT at +2*768^2
    const u16* __restrict__ bias_c,   // bk at +768, bv at +1536
    u16* __restrict__ sT, float* __restrict__ z)
{
  __shared__ char sm[32768];
  u16* T0 = (u16*)sm;                 // 4 stage tiles [64][64] bf16, chunk-swizzled
  u16* Pt = (u16*)sm;                 // overlay after GEMM: [64][72]
  u16* Vt = (u16*)(sm + 9216);        // [64][72]
  const int x = blockIdx.x;           // b*12 + n
  const int b = x / 12, n = x % 12;
  const int t = threadIdx.x, wave = t >> 6, lane = t & 63;
  const u16* srcs[4] = {
    key_ds + (size_t)b * 49152,
    WT + 589824 + (size_t)n * 49152,
    key_ds + 1572864 + (size_t)b * 49152,
    WT + 2 * 589824 + (size_t)n * 49152 };
  const int grow = lane >> 3;
  const int gchunk = (lane & 7) ^ (grow & 7);
  const int isV = wave & 1;
  const int wm = (wave >> 1) * 32;
  u16* Atile = T0 + (isV ? 2 : 0) * 4096;
  u16* Btile = T0 + (isV ? 3 : 1) * 4096;
  const int lrow = lane & 15, quad = lane >> 4;
  f32x4 acc[2][4] = {};

  for (int k0 = 0; k0 < 768; k0 += 64) {
    const u16* s = srcs[wave];
    u16* dtile = T0 + wave * 4096;
    #pragma unroll
    for (int j = 0; j < 8; ++j) {
      const u16* gsrc = s + (size_t)(j * 8 + grow) * 768 + k0 + gchunk * 8;
      GLDS16(gsrc, (char*)dtile + j * 1024);
    }
    __syncthreads();
    #pragma unroll
    for (int c = 0; c < 2; ++c) {
      bf16x8 av[2], bv[4];
      #pragma unroll
      for (int i = 0; i < 2; ++i) {
        const int row = wm + i * 16 + lrow;
        av[i] = *(const bf16x8*)&Atile[row * 64 + (((c * 4 + quad) ^ (row & 7)) * 8)];
      }
      #pragma unroll
      for (int j = 0; j < 4; ++j) {
        const int row = j * 16 + lrow;
        bv[j] = *(const bf16x8*)&Btile[row * 64 + (((c * 4 + quad) ^ (row & 7)) * 8)];
      }
      #pragma unroll
      for (int i = 0; i < 2; ++i)
        #pragma unroll
        for (int j = 0; j < 4; ++j)
          acc[i][j] = __builtin_amdgcn_mfma_f32_16x16x32_bf16(av[i], bv[j], acc[i][j], 0, 0, 0);
    }
    __syncthreads();
  }

  const u16* bias = bias_c + (isV ? 1536 : 768) + n * 64;
  u16* Ttile = isV ? Vt : Pt;
  #pragma unroll
  for (int i = 0; i < 2; ++i)
    #pragma unroll
    for (int j = 0; j < 4; ++j) {
      const int col = j * 16 + lrow;
      const float badd = bf2f(bias[col]);
      u16x4 pk4;
      #pragma unroll
      for (int r = 0; r < 4; ++r) {
        float v = acc[i][j][r] + badd;
        if (!isV) v = v > 0.0f ? v + 1.0f : __expf(v);
        pk4[r] = f2bf(v);
      }
      *(u16x4*)&Ttile[col * 72 + wm + i * 16 + quad * 4] = pk4;
    }
  __syncthreads();

  const int wm2 = (wave >> 1) * 32, wn2 = (wave & 1) * 32;
  f32x4 a2[2][2] = {};
  #pragma unroll
  for (int c = 0; c < 2; ++c) {
    bf16x8 av[2], bv[2];
    #pragma unroll
    for (int i = 0; i < 2; ++i)
      av[i] = *(const bf16x8*)&Vt[(wm2 + i * 16 + lrow) * 72 + c * 32 + quad * 8];
    #pragma unroll
    for (int j = 0; j < 2; ++j)
      bv[j] = *(const bf16x8*)&Pt[(wn2 + j * 16 + lrow) * 72 + c * 32 + quad * 8];
    #pragma unroll
    for (int i = 0; i < 2; ++i)
      #pragma unroll
      for (int j = 0; j < 2; ++j)
        a2[i][j] = __builtin_amdgcn_mfma_f32_16x16x32_bf16(av[i], bv[j], a2[i][j], 0, 0, 0);
  }
  u16* sTg = sT + (size_t)x * 4096;
  #pragma unroll
  for (int i = 0; i < 2; ++i)
    #pragma unroll
    for (int j = 0; j < 2; ++j)
      #pragma unroll
      for (int r = 0; r < 4; ++r)
        sTg[(size_t)(wm2 + i * 16 + quad * 4 + r) * 64 + wn2 + j * 16 + lrow] = f2bf(a2[i][j][r]);
  if (t < 64) {
    float zz = 0.f;
    #pragma unroll
    for (int g = 0; g < 8; ++g) {
      u16x8 p = *(const u16x8*)&Pt[t * 72 + g * 8];
      #pragma unroll
      for (int e = 0; e < 8; ++e) zz += bf2f(p[e]);
    }
    z[(size_t)x * 64 + t] = zz;
  }
}

// ---------------- a_v = (phi_q @ s) / (phi_q . z + eps), fused qz, in-place (R6) --------
__global__ __launch_bounds__(256) void attn_av_k(
    u16* __restrict__ phi_q, const u16* __restrict__ sT, const float* __restrict__ zbuf)
{
  __shared__ u16 As[64 * 72];
  __shared__ u16 Bs[64 * 72];
  __shared__ float zv[64];
  __shared__ float zpart[4][64];
  __shared__ float zq[64];
  const int x = blockIdx.x, y = blockIdx.y;
  const int b = y / 12, n = y % 12;
  const int t = threadIdx.x;
  u16* Abase = phi_q + (size_t)b * 512 * 768 + (size_t)x * 64 * 768 + n * 64;
  const u16* Bbase = sT + (size_t)y * 4096;
  if (t < 64) zv[t] = zbuf[(size_t)y * 64 + t];
  #pragma unroll
  for (int p = 0; p < 2; ++p) {
    int v = t + p * 256;
    int r = v >> 3, c = (v & 7) * 8;
    *(u16x8*)&As[r * 72 + c] = *(const u16x8*)&Abase[(size_t)r * 768 + c];
    *(u16x8*)&Bs[r * 72 + c] = *(const u16x8*)&Bbase[r * 64 + c];
  }
  __syncthreads();
  {
    int r = t & 63, seg = t >> 6;
    float s = 0.f;
    #pragma unroll
    for (int j = 0; j < 16; ++j) s += bf2f(As[r * 72 + seg * 16 + j]) * zv[seg * 16 + j];
    zpart[seg][r] = s;
  }
  __syncthreads();
  if (t < 64) {
    float s = zpart[0][t] + zpart[1][t] + zpart[2][t] + zpart[3][t];
    zq[t] = 1.0f / (s + 1e-6f);
  }
  const int wave = t >> 6, lane = t & 63;
  const int wm = (wave >> 1) * 32, wn = (wave & 1) * 32;
  const int lrow = lane & 15, quad = lane >> 4;
  f32x4 acc[2][2] = {};
  #pragma unroll
  for (int c = 0; c < 2; ++c) {
    bf16x8 av[2], bv[2];
    #pragma unroll
    for (int i = 0; i < 2; ++i) av[i] = *(const bf16x8*)&As[(wm + i * 16 + lrow) * 72 + c * 32 + quad * 8];
    #pragma unroll
    for (int j = 0; j < 2; ++j) bv[j] = *(const bf16x8*)&Bs[(wn + j * 16 + lrow) * 72 + c * 32 + quad * 8];
    #pragma unroll
    for (int i = 0; i < 2; ++i)
      #pragma unroll
      for (int j = 0; j < 2; ++j)
        acc[i][j] = __builtin_amdgcn_mfma_f32_16x16x32_bf16(av[i], bv[j], acc[i][j], 0, 0, 0);
  }
  __syncthreads();
  #pragma unroll
  for (int i = 0; i < 2; ++i)
    #pragma unroll
    for (int j = 0; j < 2; ++j) {
      const int col = wn + j * 16 + lrow;
      #pragma unroll
      for (int r = 0; r < 4; ++r) {
        const int row = wm + i * 16 + quad * 4 + r;
        Abase[(size_t)row * 768 + col] = f2bf(acc[i][j][r] * zq[row]);
      }
    }
}

__global__ void tagfill_k(float* out, float val, int n) {
  int i = blockIdx.x * 256 + threadIdx.x;
  if (i < n) out[i] = val;
}

extern "C" void kernel_launch(void* const* d_in, const int* in_sizes, int n_in,
                              void* d_out, int out_size, void* d_ws, size_t ws_size,
                              hipStream_t stream) {
  (void)out_size;
  float* out = (float*)d_out;

  int o;
  if (n_in >= 14 && in_sizes[3] == 1) o = 4;
  else if (n_in == 13) o = 3;
  else { tagfill_k<<<4, 256, 0, stream>>>(out, 77.0f, 1024); return; }
  if (in_sizes[0] != 12582912 || in_sizes[o + 0] != 32768 || in_sizes[o + 2] != 589824) {
    tagfill_k<<<4, 256, 0, stream>>>(out, 88.0f, 1024); return;
  }

  const float* query = (const float*)d_in[0];
  const float* key   = (const float*)d_in[1];
  const float* value = (const float*)d_in[2];
  const float* W_kds = (const float*)d_in[o + 0];
  const float* W_vds = (const float*)d_in[o + 1];
  const float* Wq   = (const float*)d_in[o + 2];
  const float* bq   = (const float*)d_in[o + 3];
  const float* Wk   = (const float*)d_in[o + 4];
  const float* bk   = (const float*)d_in[o + 5];
  const float* Wv   = (const float*)d_in[o + 6];
  const float* bv   = (const float*)d_in[o + 7];
  const float* Wout = (const float*)d_in[o + 8];
  const float* bout = (const float*)d_in[o + 9];

  const size_t NEED = 61478912;
  if (ws_size < NEED) { tagfill_k<<<4, 256, 0, stream>>>(out, 123.0f, 1024); return; }

  char* base = (char*)d_ws;
  u16*   WT     = (u16*)base;                         // 4,718,592
  char*  Breg   = base + 4718592;                     // 25,165,824 region
  u16*   q_bf   = (u16*)Breg;                         // dies after phi_q GEMM
  u16*   sT     = (u16*)Breg;                         // then sT (over dead q_bf)
  float* zbuf   = (float*)(Breg + 3145728);
  u16*   phi_q  = (u16*)(base + 29884416);            // 25,165,824
  u16*   Wds_c  = (u16*)(base + 55050240);            // 131,072
  u16*   bias_c = (u16*)(base + 55181312);            // 6,144
  u16*   key_ds = (u16*)(base + 55187456);            // 6,291,456
  u16* a_v = phi_q;
  u16* WqT   = WT;
  u16* WoutT = WT + 3 * 768 * 768;
  u16* bq_c = bias_c, *bout_c = bias_c + 2304;

  // 1. prep: W transposes + query cvt + Wds/bias cvt
  prep_k<<<6988, 256, 0, stream>>>(Wq, Wk, Wv, Wout, query, W_kds, W_vds,
                                   bq, bk, bv, bout, WT, q_bf, Wds_c, bias_c);

  // 2. phi_q = elu(q_bf @ WqT + bq) + 1  (bf16 A, GLDS, BK=64)
  gemm64_k<1, false><<<768, 256, 0, stream>>>(
      q_bf, 768, WqT, 768, phi_q, 768, bq_c, 768);

  // 3. downsample (N-tile 32: 1536 blocks, 6/CU)
  ds_k<<<dim3(24, 64), 256, 0, stream>>>(Wds_c, key, value, key_ds);

  // 4. fused phi_k/vals + KV state (R8-exact; sT/zbuf overwrite dead q_bf)
  fkv_k<<<384, 256, 0, stream>>>(key_ds, WT, bias_c, sT, zbuf);

  // 5. a_v = (phi_q @ s) * 1/(phi_q.z+eps), fused qz, in-place
  attn_av_k<<<dim3(8, 384), 256, 0, stream>>>(phi_q, sT, zbuf);

  // 6. out = a_v @ Wout + bout (fp32 C, XCD-swizzled)
  gemm64_k<0, true><<<768, 256, 0, stream>>>(
      a_v, 768, WoutT, 768, out, 768, bout_c, 768);
}

// Round 12
// 294.926 us; speedup vs baseline: 1.0839x; 1.0134x over previous
//
#include <hip/hip_runtime.h>

typedef unsigned short u16;
typedef u16 u16x4 __attribute__((ext_vector_type(4)));
typedef u16 u16x8 __attribute__((ext_vector_type(8)));
typedef __bf16 bf16;
typedef bf16 bf16x8 __attribute__((ext_vector_type(8)));
typedef float f32x4 __attribute__((ext_vector_type(4)));

__device__ __forceinline__ float bf2f(u16 v) {
  union { unsigned u; float f; } x; x.u = ((unsigned)v) << 16; return x.f;
}
__device__ __forceinline__ u16 f2bf(float f) {
  union { float f; unsigned u; } x; x.f = f;
  unsigned u = x.u;
  u += 0x7fffu + ((u >> 16) & 1u);   // RNE
  return (u16)(u >> 16);
}

// lgkm-only barrier: LDS drained, global loads stay in flight
__device__ __forceinline__ void bar_lgkm() {
  asm volatile("s_waitcnt lgkmcnt(0)" ::: "memory");
  __builtin_amdgcn_s_barrier();
}

// async global->LDS, 16B per lane; LDS base wave-uniform, global source per-lane (m173)
#define GLDS16(g, l) __builtin_amdgcn_global_load_lds( \
    (const __attribute__((address_space(1))) unsigned int*)(const void*)(g), \
    (__attribute__((address_space(3))) unsigned int*)(void*)(l), 16, 0, 0)

// ---------------- prep: 4 weight transposes + query cvt + small cvts (R0/R8 proven) -----
// grid 6988: [0,576) transpose4; [576,6720) query fp32->bf16; [6720,6988) small converts
__global__ __launch_bounds__(256) void prep_k(
    const float* __restrict__ Wq, const float* __restrict__ Wk,
    const float* __restrict__ Wv, const float* __restrict__ Wout,
    const float* __restrict__ query,
    const float* __restrict__ wkds, const float* __restrict__ wvds,
    const float* __restrict__ b0, const float* __restrict__ b1,
    const float* __restrict__ b2, const float* __restrict__ b3,
    u16* __restrict__ WT, u16* __restrict__ q_bf,
    u16* __restrict__ dstW, u16* __restrict__ dstB)
{
  __shared__ u16 T[64][72];
  const int blk = blockIdx.x;
  const int t = threadIdx.x;
  if (blk < 576) {
    const int bz = blk / 144, rr = blk % 144;
    const int r0 = (rr / 12) * 64, c0 = (rr % 12) * 64;
    const float* W = (bz == 0) ? Wq : (bz == 1) ? Wk : (bz == 2) ? Wv : Wout;
    u16* O = WT + (size_t)bz * 768 * 768;
    #pragma unroll
    for (int p = 0; p < 2; ++p) {
      int v = t + p * 256;
      int r = v / 8, c = (v % 8) * 8;
      f32x4 x0 = *(const f32x4*)&W[(size_t)(r0 + r) * 768 + c0 + c];
      f32x4 x1 = *(const f32x4*)&W[(size_t)(r0 + r) * 768 + c0 + c + 4];
      #pragma unroll
      for (int i = 0; i < 4; ++i) { T[r][c + i] = f2bf(x0[i]); T[r][c + 4 + i] = f2bf(x1[i]); }
    }
    __syncthreads();
    #pragma unroll
    for (int p = 0; p < 2; ++p) {
      int v = t + p * 256;
      int r = v / 8, c = (v % 8) * 8;
      u16x8 tv;
      #pragma unroll
      for (int i = 0; i < 8; ++i) tv[i] = T[c + i][r];
      *(u16x8*)&O[(size_t)(c0 + r) * 768 + r0 + c] = tv;
    }
  } else if (blk < 6720) {
    const size_t i = (size_t)(blk - 576) * 256 + t;   // 6144*256 slots, *8 = 12582912
    f32x4 a = *(const f32x4*)&query[i * 8];
    f32x4 b = *(const f32x4*)&query[i * 8 + 4];
    u16x8 w;
    #pragma unroll
    for (int j = 0; j < 4; ++j) { w[j] = f2bf(a[j]); w[4 + j] = f2bf(b[j]); }
    *(u16x8*)&q_bf[i * 8] = w;
  } else {
    const int i = (blk - 6720) * 256 + t;   // 268*256 = 68608 = 65536 + 3072
    if (i < 32768)      dstW[i] = f2bf(wkds[i]);
    else if (i < 65536) dstW[i] = f2bf(wvds[i - 32768]);
    else {
      int j = i - 65536, s = j / 768, si = j % 768;
      const float* src = (s == 0) ? b0 : (s == 1) ? b1 : (s == 2) ? b2 : b3;
      dstB[j] = f2bf(src[si]);
    }
  }
}

// ---------------- downsample v6: N=32 grid + 2-DEEP register prefetch ----------------
// 5 variants showed ds invariant at ~50us: 1-deep prefetch (~300cy cover) can't hide
// ~900cy load latency; every step exposes ~600cy x 16 steps. 2-deep: loads for step
// k+2 issued at step k (breg[2][4], fully unrolled -> static indexing, no scratch).
__global__ __launch_bounds__(256) void ds_k(
    const u16* __restrict__ Wds,      // bf16 [2][64][512]
    const float* __restrict__ key, const float* __restrict__ value,
    u16* __restrict__ key_ds)         // [2][32][64][768] (key_ds ++ val_ds contiguous)
{
  __shared__ u16 Bs[2][32 * 40];     // 5KB, [buf][n][k] stride 40
  const int pair = blockIdx.y >> 5, b = blockIdx.y & 31;
  const float* src = (pair ? value : key) + (size_t)b * 512 * 768;
  const u16* W = Wds + pair * 32768;
  u16* dst = key_ds + (size_t)pair * 1572864 + (size_t)b * 49152;
  const int nt = blockIdx.x * 32;
  const int t = threadIdx.x, wave = t >> 6, lane = t & 63;
  const int wm = wave * 16;                    // 4 waves x 16 kds-rows
  const int lrow = lane & 15, quad = lane >> 4;
  const int bn = t & 31, bk4 = (t >> 5) * 4;   // owned column, 4-row k-group
  const float* bcol = src + nt + bn;

  f32x4 acc[2] = {};
  float breg[2][4];
  bf16x8 av[2];

  #pragma unroll
  for (int i = 0; i < 4; ++i) breg[0][i] = bcol[(size_t)(bk4 + i) * 768];
  #pragma unroll
  for (int i = 0; i < 4; ++i) breg[1][i] = bcol[(size_t)(32 + bk4 + i) * 768];
  av[0] = *(const bf16x8*)&W[(size_t)(wm + lrow) * 512 + quad * 8];

  #pragma unroll
  for (int step = 0; step < 16; ++step) {
    const int cur = step & 1, nxt = cur ^ 1;
    u16x4 wv;
    #pragma unroll
    for (int i = 0; i < 4; ++i) wv[i] = f2bf(breg[cur][i]);   // waits loads from step-2
    *(u16x4*)&Bs[cur][bn * 40 + bk4] = wv;
    if (step < 14) {
      const int k2 = (step + 2) * 32;
      #pragma unroll
      for (int i = 0; i < 4; ++i) breg[cur][i] = bcol[(size_t)(k2 + bk4 + i) * 768];
    }
    if (step < 15)
      av[nxt] = *(const bf16x8*)&W[(size_t)(wm + lrow) * 512 + (step + 1) * 32 + quad * 8];
    bar_lgkm();   // LDS writes visible; global prefetch stays in flight
    bf16x8 bv[2];
    #pragma unroll
    for (int j = 0; j < 2; ++j)
      bv[j] = *(const bf16x8*)&Bs[cur][(j * 16 + lrow) * 40 + quad * 8];
    #pragma unroll
    for (int j = 0; j < 2; ++j)
      acc[j] = __builtin_amdgcn_mfma_f32_16x16x32_bf16(av[cur], bv[j], acc[j], 0, 0, 0);
    // read(step,buf) vs write(step+2,buf) separated by step+1's barrier: dbuf safe
  }

  #pragma unroll
  for (int j = 0; j < 2; ++j) {
    const int col = nt + j * 16 + lrow;
    #pragma unroll
    for (int r = 0; r < 4; ++r) {
      const int row = wm + quad * 4 + r;
      dst[(size_t)row * 768 + col] = f2bf(acc[j][r]);
    }
  }
}

// ---------------- bf16 GEMM, BK=64, GLDS, swizzled, XCD-chunked (R6 proven) ----------
template<int ACT, bool OF32>
__global__ __launch_bounds__(256) void gemm64_k(
    const u16* __restrict__ A, int lda,
    const u16* __restrict__ Bt, int ldb,
    void* __restrict__ Craw, int ldc,
    const u16* __restrict__ bias, int K)
{
  __shared__ u16 As[128 * 64];   // 16KB, swizzled ch^(r&7)
  __shared__ u16 Bs[128 * 64];   // 16KB, swizzled
  const int blk = blockIdx.x;                   // 768 = 128 mt x 6 nt
  const int wg = (blk & 7) * 96 + (blk >> 3);
  const int mt = (wg / 6) * 128, nt = (wg % 6) * 128;
  const int t = threadIdx.x, wave = t >> 6, lane = t & 63;
  const int wm = (wave >> 1) * 64, wn = (wave & 1) * 64;
  const int lrow = lane & 15, quad = lane >> 4;
  f32x4 acc[4][4] = {};

  for (int k0 = 0; k0 < K; k0 += 64) {
    __syncthreads();
    #pragma unroll
    for (int p = 0; p < 4; ++p) {
      const int slot = wave * 256 + p * 64 + lane;
      const int r = slot >> 3, ch = slot & 7;
      const int chs = ch ^ (r & 7);
      const int lb = (wave * 256 + p * 64) * 8;
      GLDS16(&A[(size_t)(mt + r) * lda + k0 + chs * 8], &As[lb]);
      GLDS16(&Bt[(size_t)(nt + r) * ldb + k0 + chs * 8], &Bs[lb]);
    }
    __syncthreads();

    #pragma unroll
    for (int c = 0; c < 2; ++c) {
      bf16x8 av[4], bv[4];
      #pragma unroll
      for (int i = 0; i < 4; ++i) {
        const int row = wm + i * 16 + lrow;
        av[i] = *(const bf16x8*)&As[row * 64 + (((c * 4 + quad) ^ (row & 7)) * 8)];
      }
      #pragma unroll
      for (int j = 0; j < 4; ++j) {
        const int row = wn + j * 16 + lrow;
        bv[j] = *(const bf16x8*)&Bs[row * 64 + (((c * 4 + quad) ^ (row & 7)) * 8)];
      }
      #pragma unroll
      for (int i = 0; i < 4; ++i)
        #pragma unroll
        for (int j = 0; j < 4; ++j)
          acc[i][j] = __builtin_amdgcn_mfma_f32_16x16x32_bf16(av[i], bv[j], acc[i][j], 0, 0, 0);
    }
  }

  #pragma unroll
  for (int i = 0; i < 4; ++i) {
    #pragma unroll
    for (int j = 0; j < 4; ++j) {
      const int col = nt + wn + j * 16 + lrow;
      const float badd = bias ? bf2f(bias[col]) : 0.0f;
      #pragma unroll
      for (int r = 0; r < 4; ++r) {
        const int row = mt + wm + i * 16 + quad * 4 + r;
        float v = acc[i][j][r] + badd;
        if constexpr (ACT == 1) v = v > 0.0f ? v + 1.0f : __expf(v);
        if constexpr (OF32) ((float*)Craw)[(size_t)row * ldc + col] = v;
        else                ((u16*)Craw)[(size_t)row * ldc + col] = f2bf(v);
      }
    }
  }
}

// ---------------- fused phi_k/vals GEMM + KV-state, double-buffered (bug-fixed) ----------
// Stage(k+1) issued BEFORE compute(k): GLDS latency hidden under 16 MFMA; ONE barrier
// per step (12 vs 24). Buffers: tile = 8192 B, buffer = 4 tiles = 32768 B, total 64 KB
// (R7's proven static-LDS size). Pt/Vt epilogue overlays dead buffer 0 after final barrier.
__global__ __launch_bounds__(256) void fkv_k(
    const u16* __restrict__ key_ds,   // [2][32][64][768] bf16
    const u16* __restrict__ WT,       // WkT at +768^2, WvT at +2*768^2
    const u16* __restrict__ bias_c,   // bk at +768, bv at +1536
    u16* __restrict__ sT, float* __restrict__ z)
{
  __shared__ char sm[65536];
  u16* T0 = (u16*)sm;                 // buf b: u16 offset b*16384; tile w: +w*4096
  u16* Pt = (u16*)sm;                 // [64][72] overlay after loop
  u16* Vt = (u16*)(sm + 9216);        // [64][72]
  const int x = blockIdx.x;           // b*12 + n
  const int b = x / 12, n = x % 12;
  const int t = threadIdx.x, wave = t >> 6, lane = t & 63;
  const u16* srcs[4] = {
    key_ds + (size_t)b * 49152,
    WT + 589824 + (size_t)n * 49152,
    key_ds + 1572864 + (size_t)b * 49152,
    WT + 2 * 589824 + (size_t)n * 49152 };
  const int grow = lane >> 3;
  const int gchunk = (lane & 7) ^ (grow & 7);
  const int isV = wave & 1;
  const int wm = (wave >> 1) * 32;
  const int lrow = lane & 15, quad = lane >> 4;
  f32x4 acc[2][4] = {};

  auto stage = [&](int buf, int k0) {   // wave w loads tile w into buffer buf
    const u16* s = srcs[wave];
    char* dtile = sm + buf * 32768 + wave * 8192;   // tile = 64x64 bf16 = 8192 B
    #pragma unroll
    for (int j = 0; j < 8; ++j) {
      const u16* gsrc = s + (size_t)(j * 8 + grow) * 768 + k0 + gchunk * 8;
      GLDS16(gsrc, dtile + j * 1024);
    }
  };

  stage(0, 0);
  __syncthreads();
  int buf = 0;
  for (int ks = 0; ks < 12; ++ks) {
    if (ks < 11) stage(buf ^ 1, (ks + 1) * 64);   // flies during MFMA below
    const u16* Atile = T0 + buf * 16384 + (isV ? 2 : 0) * 4096;
    const u16* Btile = T0 + buf * 16384 + (isV ? 3 : 1) * 4096;
    #pragma unroll
    for (int c = 0; c < 2; ++c) {
      bf16x8 av[2], bv[4];
      #pragma unroll
      for (int i = 0; i < 2; ++i) {
        const int row = wm + i * 16 + lrow;
        av[i] = *(const bf16x8*)&Atile[row * 64 + (((c * 4 + quad) ^ (row & 7)) * 8)];
      }
      #pragma unroll
      for (int j = 0; j < 4; ++j) {
        const int row = j * 16 + lrow;
        bv[j] = *(const bf16x8*)&Btile[row * 64 + (((c * 4 + quad) ^ (row & 7)) * 8)];
      }
      #pragma unroll
      for (int i = 0; i < 2; ++i)
        #pragma unroll
        for (int j = 0; j < 4; ++j)
          acc[i][j] = __builtin_amdgcn_mfma_f32_16x16x32_bf16(av[i], bv[j], acc[i][j], 0, 0, 0);
    }
    __syncthreads();   // drains GLDS(buf^1) + this step's LDS reads
    buf ^= 1;
  }

  const u16* bias = bias_c + (isV ? 1536 : 768) + n * 64;
  u16* Ttile = isV ? Vt : Pt;
  #pragma unroll
  for (int i = 0; i < 2; ++i)
    #pragma unroll
    for (int j = 0; j < 4; ++j) {
      const int col = j * 16 + lrow;
      const float badd = bf2f(bias[col]);
      u16x4 pk4;
      #pragma unroll
      for (int r = 0; r < 4; ++r) {
        float v = acc[i][j][r] + badd;
        if (!isV) v = v > 0.0f ? v + 1.0f : __expf(v);
        pk4[r] = f2bf(v);
      }
      *(u16x4*)&Ttile[col * 72 + wm + i * 16 + quad * 4] = pk4;
    }
  __syncthreads();

  const int wm2 = (wave >> 1) * 32, wn2 = (wave & 1) * 32;
  f32x4 a2[2][2] = {};
  #pragma unroll
  for (int c = 0; c < 2; ++c) {
    bf16x8 av[2], bv[2];
    #pragma unroll
    for (int i = 0; i < 2; ++i)
      av[i] = *(const bf16x8*)&Vt[(wm2 + i * 16 + lrow) * 72 + c * 32 + quad * 8];
    #pragma unroll
    for (int j = 0; j < 2; ++j)
      bv[j] = *(const bf16x8*)&Pt[(wn2 + j * 16 + lrow) * 72 + c * 32 + quad * 8];
    #pragma unroll
    for (int i = 0; i < 2; ++i)
      #pragma unroll
      for (int j = 0; j < 2; ++j)
        a2[i][j] = __builtin_amdgcn_mfma_f32_16x16x32_bf16(av[i], bv[j], a2[i][j], 0, 0, 0);
  }
  u16* sTg = sT + (size_t)x * 4096;
  #pragma unroll
  for (int i = 0; i < 2; ++i)
    #pragma unroll
    for (int j = 0; j < 2; ++j)
      #pragma unroll
      for (int r = 0; r < 4; ++r)
        sTg[(size_t)(wm2 + i * 16 + quad * 4 + r) * 64 + wn2 + j * 16 + lrow] = f2bf(a2[i][j][r]);
  if (t < 64) {
    float zz = 0.f;
    #pragma unroll
    for (int g = 0; g < 8; ++g) {
      u16x8 p = *(const u16x8*)&Pt[t * 72 + g * 8];
      #pragma unroll
      for (int e = 0; e < 8; ++e) zz += bf2f(p[e]);
    }
    z[(size_t)x * 64 + t] = zz;
  }
}

// ---------------- a_v = (phi_q @ s) / (phi_q . z + eps), fused qz, in-place (R6) --------
__global__ __launch_bounds__(256) void attn_av_k(
    u16* __restrict__ phi_q, const u16* __restrict__ sT, const float* __restrict__ zbuf)
{
  __shared__ u16 As[64 * 72];
  __shared__ u16 Bs[64 * 72];
  __shared__ float zv[64];
  __shared__ float zpart[4][64];
  __shared__ float zq[64];
  const int x = blockIdx.x, y = blockIdx.y;
  const int b = y / 12, n = y % 12;
  const int t = threadIdx.x;
  u16* Abase = phi_q + (size_t)b * 512 * 768 + (size_t)x * 64 * 768 + n * 64;
  const u16* Bbase = sT + (size_t)y * 4096;
  if (t < 64) zv[t] = zbuf[(size_t)y * 64 + t];
  #pragma unroll
  for (int p = 0; p < 2; ++p) {
    int v = t + p * 256;
    int r = v >> 3, c = (v & 7) * 8;
    *(u16x8*)&As[r * 72 + c] = *(const u16x8*)&Abase[(size_t)r * 768 + c];
    *(u16x8*)&Bs[r * 72 + c] = *(const u16x8*)&Bbase[r * 64 + c];
  }
  __syncthreads();
  {
    int r = t & 63, seg = t >> 6;
    float s = 0.f;
    #pragma unroll
    for (int j = 0; j < 16; ++j) s += bf2f(As[r * 72 + seg * 16 + j]) * zv[seg * 16 + j];
    zpart[seg][r] = s;
  }
  __syncthreads();
  if (t < 64) {
    float s = zpart[0][t] + zpart[1][t] + zpart[2][t] + zpart[3][t];
    zq[t] = 1.0f / (s + 1e-6f);
  }
  const int wave = t >> 6, lane = t & 63;
  const int wm = (wave >> 1) * 32, wn = (wave & 1) * 32;
  const int lrow = lane & 15, quad = lane >> 4;
  f32x4 acc[2][2] = {};
  #pragma unroll
  for (int c = 0; c < 2; ++c) {
    bf16x8 av[2], bv[2];
    #pragma unroll
    for (int i = 0; i < 2; ++i) av[i] = *(const bf16x8*)&As[(wm + i * 16 + lrow) * 72 + c * 32 + quad * 8];
    #pragma unroll
    for (int j = 0; j < 2; ++j) bv[j] = *(const bf16x8*)&Bs[(wn + j * 16 + lrow) * 72 + c * 32 + quad * 8];
    #pragma unroll
    for (int i = 0; i < 2; ++i)
      #pragma unroll
      for (int j = 0; j < 2; ++j)
        acc[i][j] = __builtin_amdgcn_mfma_f32_16x16x32_bf16(av[i], bv[j], acc[i][j], 0, 0, 0);
  }
  __syncthreads();
  #pragma unroll
  for (int i = 0; i < 2; ++i)
    #pragma unroll
    for (int j = 0; j < 2; ++j) {
      const int col = wn + j * 16 + lrow;
      #pragma unroll
      for (int r = 0; r < 4; ++r) {
        const int row = wm + i * 16 + quad * 4 + r;
        Abase[(size_t)row * 768 + col] = f2bf(acc[i][j][r] * zq[row]);
      }
    }
}

__global__ void tagfill_k(float* out, float val, int n) {
  int i = blockIdx.x * 256 + threadIdx.x;
  if (i < n) out[i] = val;
}

extern "C" void kernel_launch(void* const* d_in, const int* in_sizes, int n_in,
                              void* d_out, int out_size, void* d_ws, size_t ws_size,
                              hipStream_t stream) {
  (void)out_size;
  float* out = (float*)d_out;

  int o;
  if (n_in >= 14 && in_sizes[3] == 1) o = 4;
  else if (n_in == 13) o = 3;
  else { tagfill_k<<<4, 256, 0, stream>>>(out, 77.0f, 1024); return; }
  if (in_sizes[0] != 12582912 || in_sizes[o + 0] != 32768 || in_sizes[o + 2] != 589824) {
    tagfill_k<<<4, 256, 0, stream>>>(out, 88.0f, 1024); return;
  }

  const float* query = (const float*)d_in[0];
  const float* key   = (const float*)d_in[1];
  const float* value = (const float*)d_in[2];
  const float* W_kds = (const float*)d_in[o + 0];
  const float* W_vds = (const float*)d_in[o + 1];
  const float* Wq   = (const float*)d_in[o + 2];
  const float* bq   = (const float*)d_in[o + 3];
  const float* Wk   = (const float*)d_in[o + 4];
  const float* bk   = (const float*)d_in[o + 5];
  const float* Wv   = (const float*)d_in[o + 6];
  const float* bv   = (const float*)d_in[o + 7];
  const float* Wout = (const float*)d_in[o + 8];
  const float* bout = (const float*)d_in[o + 9];

  const size_t NEED = 61478912;
  if (ws_size < NEED) { tagfill_k<<<4, 256, 0, stream>>>(out, 123.0f, 1024); return; }

  char* base = (char*)d_ws;
  u16*   WT     = (u16*)base;                         // 4,718,592
  char*  Breg   = base + 4718592;                     // 25,165,824 region
  u16*   q_bf   = (u16*)Breg;                         // dies after phi_q GEMM
  u16*   sT     = (u16*)Breg;                         // then sT (over dead q_bf)
  float* zbuf   = (float*)(Breg + 3145728);
  u16*   phi_q  = (u16*)(base + 29884416);            // 25,165,824
  u16*   Wds_c  = (u16*)(base + 55050240);            // 131,072
  u16*   bias_c = (u16*)(base + 55181312);            // 6,144
  u16*   key_ds = (u16*)(base + 55187456);            // 6,291,456
  u16* a_v = phi_q;
  u16* WqT   = WT;
  u16* WoutT = WT + 3 * 768 * 768;
  u16* bq_c = bias_c, *bout_c = bias_c + 2304;

  // 1. prep: W transposes + query cvt + Wds/bias cvt
  prep_k<<<6988, 256, 0, stream>>>(Wq, Wk, Wv, Wout, query, W_kds, W_vds,
                                   bq, bk, bv, bout, WT, q_bf, Wds_c, bias_c);

  // 2. phi_q = elu(q_bf @ WqT + bq) + 1  (bf16 A, GLDS, BK=64)
  gemm64_k<1, false><<<768, 256, 0, stream>>>(
      q_bf, 768, WqT, 768, phi_q, 768, bq_c, 768);

  // 3. downsample (N=32 grid, 2-deep prefetch)
  ds_k<<<dim3(24, 64), 256, 0, stream>>>(Wds_c, key, value, key_ds);

  // 4. fused phi_k/vals + KV state, double-buffered (sT/zbuf overwrite dead q_bf)
  fkv_k<<<384, 256, 0, stream>>>(key_ds, WT, bias_c, sT, zbuf);

  // 5. a_v = (phi_q @ s) * 1/(phi_q.z+eps), fused qz, in-place
  attn_av_k<<<dim3(8, 384), 256, 0, stream>>>(phi_q, sT, zbuf);

  // 6. out = a_v @ Wout + bout (fp32 C, XCD-swizzled)
  gemm64_k<0, true><<<768, 256, 0, stream>>>(
      a_v, 768, WoutT, 768, out, 768, bout_c, 768);
}

// Round 13
// 293.194 us; speedup vs baseline: 1.0903x; 1.0059x over previous
//
#include <hip/hip_runtime.h>

typedef unsigned short u16;
typedef u16 u16x4 __attribute__((ext_vector_type(4)));
typedef u16 u16x8 __attribute__((ext_vector_type(8)));
typedef __bf16 bf16;
typedef bf16 bf16x8 __attribute__((ext_vector_type(8)));
typedef float f32x4 __attribute__((ext_vector_type(4)));

__device__ __forceinline__ float bf2f(u16 v) {
  union { unsigned u; float f; } x; x.u = ((unsigned)v) << 16; return x.f;
}
__device__ __forceinline__ u16 f2bf(float f) {
  union { float f; unsigned u; } x; x.f = f;
  unsigned u = x.u;
  u += 0x7fffu + ((u >> 16) & 1u);   // RNE
  return (u16)(u >> 16);
}
// hw packed f32->bf16 (RNE), 2 values / instr (no builtin on gfx950, m240)
__device__ __forceinline__ unsigned cvt2bf(float lo, float hi) {
  unsigned r;
  asm("v_cvt_pk_bf16_f32 %0, %1, %2" : "=v"(r) : "v"(lo), "v"(hi));
  return r;
}

// lgkm-only barrier: LDS drained, global loads stay in flight
__device__ __forceinline__ void bar_lgkm() {
  asm volatile("s_waitcnt lgkmcnt(0)" ::: "memory");
  __builtin_amdgcn_s_barrier();
}

// async global->LDS, 16B per lane; LDS base wave-uniform, global source per-lane (m173)
#define GLDS16(g, l) __builtin_amdgcn_global_load_lds( \
    (const __attribute__((address_space(1))) unsigned int*)(const void*)(g), \
    (__attribute__((address_space(3))) unsigned int*)(void*)(l), 16, 0, 0)

// ---------------- prep: 4 weight transposes + query cvt + small cvts (R0/R8 proven) -----
__global__ __launch_bounds__(256) void prep_k(
    const float* __restrict__ Wq, const float* __restrict__ Wk,
    const float* __restrict__ Wv, const float* __restrict__ Wout,
    const float* __restrict__ query,
    const float* __restrict__ wkds, const float* __restrict__ wvds,
    const float* __restrict__ b0, const float* __restrict__ b1,
    const float* __restrict__ b2, const float* __restrict__ b3,
    u16* __restrict__ WT, u16* __restrict__ q_bf,
    u16* __restrict__ dstW, u16* __restrict__ dstB)
{
  __shared__ u16 T[64][72];
  const int blk = blockIdx.x;
  const int t = threadIdx.x;
  if (blk < 576) {
    const int bz = blk / 144, rr = blk % 144;
    const int r0 = (rr / 12) * 64, c0 = (rr % 12) * 64;
    const float* W = (bz == 0) ? Wq : (bz == 1) ? Wk : (bz == 2) ? Wv : Wout;
    u16* O = WT + (size_t)bz * 768 * 768;
    #pragma unroll
    for (int p = 0; p < 2; ++p) {
      int v = t + p * 256;
      int r = v / 8, c = (v % 8) * 8;
      f32x4 x0 = *(const f32x4*)&W[(size_t)(r0 + r) * 768 + c0 + c];
      f32x4 x1 = *(const f32x4*)&W[(size_t)(r0 + r) * 768 + c0 + c + 4];
      #pragma unroll
      for (int i = 0; i < 4; ++i) { T[r][c + i] = f2bf(x0[i]); T[r][c + 4 + i] = f2bf(x1[i]); }
    }
    __syncthreads();
    #pragma unroll
    for (int p = 0; p < 2; ++p) {
      int v = t + p * 256;
      int r = v / 8, c = (v % 8) * 8;
      u16x8 tv;
      #pragma unroll
      for (int i = 0; i < 8; ++i) tv[i] = T[c + i][r];
      *(u16x8*)&O[(size_t)(c0 + r) * 768 + r0 + c] = tv;
    }
  } else if (blk < 6720) {
    const size_t i = (size_t)(blk - 576) * 256 + t;   // 6144*256 slots, *8 = 12582912
    f32x4 a = *(const f32x4*)&query[i * 8];
    f32x4 b = *(const f32x4*)&query[i * 8 + 4];
    u16x8 w;
    #pragma unroll
    for (int j = 0; j < 4; ++j) { w[j] = f2bf(a[j]); w[4 + j] = f2bf(b[j]); }
    *(u16x8*)&q_bf[i * 8] = w;
  } else {
    const int i = (blk - 6720) * 256 + t;   // 268*256 = 68608 = 65536 + 3072
    if (i < 32768)      dstW[i] = f2bf(wkds[i]);
    else if (i < 65536) dstW[i] = f2bf(wvds[i - 32768]);
    else {
      int j = i - 65536, s = j / 768, si = j % 768;
      const float* src = (s == 0) ? b0 : (s == 1) ? b1 : (s == 2) ? b2 : b3;
      dstB[j] = f2bf(src[si]);
    }
  }
}

// ---------------- downsample v7: COALESCED GLDS rows + LDS-side transpose ----------------
// 6 variants pinned at ~50us shared one invariant: per-lane column-walk global reads
// (4B @ stride 3072B, ~2 TB/s logical). v7 stages full fp32 rows via GLDS (coalesced,
// prep-class streaming ~5-6 TB/s), source-chunk-swizzled; transpose happens at LDS-read
// (8 strided b32 + cvt_pk per fragment, swizzle -> <=2-way banks). W preloaded to regs.
__global__ __launch_bounds__(256) void ds_k(
    const u16* __restrict__ Wds,      // bf16 [2][64][512]
    const float* __restrict__ key, const float* __restrict__ value,
    u16* __restrict__ key_ds)         // [2][32][64][768] (key_ds ++ val_ds contiguous)
{
  __shared__ float Sg[2][64 * 64];   // 16KB/buf: fp32 [k-row][64 cols], chunk-swizzled
  const int pair = blockIdx.y >> 5, b = blockIdx.y & 31;
  const float* src = (pair ? value : key) + (size_t)b * 512 * 768;
  const u16* W = Wds + pair * 32768;
  u16* dst = key_ds + (size_t)pair * 1572864 + (size_t)b * 49152;
  const int nt = blockIdx.x * 64;
  const int t = threadIdx.x, wave = t >> 6, lane = t & 63;
  const int wm = wave * 16;                    // 4 waves x 16 kds-rows
  const int lrow = lane & 15, quad = lane >> 4;

  // preload ALL W fragments for this wave's 16 rows: zero W traffic in loop (L2-hot)
  bf16x8 wreg[16];
  #pragma unroll
  for (int c = 0; c < 16; ++c)
    wreg[c] = *(const bf16x8*)&W[(size_t)(wm + lrow) * 512 + c * 32 + quad * 8];

  // stage one 64-row x 64-col fp32 chunk; GLDS g covers rows 4g..4g+3 (1KB),
  // source chunk-swizzle ch^(g&15) (wave-uniform g -> legal per-lane source perm)
  auto stage = [&](int bufi, int kb) {
    #pragma unroll
    for (int p = 0; p < 4; ++p) {
      const int g = wave * 4 + p;
      const int row = kb + g * 4 + (lane >> 4);
      const int ch = (lane & 15) ^ (g & 15);
      GLDS16(&src[(size_t)row * 768 + nt + ch * 4], (char*)&Sg[bufi][0] + g * 1024);
    }
  };

  f32x4 acc[4] = {};
  stage(0, 0);
  __syncthreads();
  #pragma unroll
  for (int cc = 0; cc < 8; ++cc) {
    const int cur = cc & 1;
    if (cc < 7) stage(cur ^ 1, (cc + 1) * 64);   // flies during transpose+MFMA below
    #pragma unroll
    for (int kc = 0; kc < 2; ++kc) {
      bf16x8 bv[4];
      #pragma unroll
      for (int j = 0; j < 4; ++j) {
        const int n = j * 16 + lrow;
        union { unsigned w[4]; bf16x8 v; } cv;
        #pragma unroll
        for (int h = 0; h < 4; ++h) {
          const int k0 = kc * 32 + quad * 8 + 2 * h;
          const int s0 = (k0 >> 2) & 15;          // same for k0,k0+1 (k0 even)
          const float lo = Sg[cur][k0 * 64 + (((n >> 2) ^ s0) * 4) + (n & 3)];
          const float hi = Sg[cur][(k0 + 1) * 64 + (((n >> 2) ^ s0) * 4) + (n & 3)];
          cv.w[h] = cvt2bf(lo, hi);
        }
        bv[j] = cv.v;
      }
      #pragma unroll
      for (int j = 0; j < 4; ++j)
        acc[j] = __builtin_amdgcn_mfma_f32_16x16x32_bf16(wreg[cc * 2 + kc], bv[j], acc[j], 0, 0, 0);
    }
    __syncthreads();   // drains next-chunk GLDS + this chunk's LDS reads
  }

  #pragma unroll
  for (int j = 0; j < 4; ++j) {
    const int col = nt + j * 16 + lrow;
    #pragma unroll
    for (int r = 0; r < 4; ++r) {
      const int row = wm + quad * 4 + r;
      dst[(size_t)row * 768 + col] = f2bf(acc[j][r]);
    }
  }
}

// ---------------- bf16 GEMM, BK=64, GLDS, swizzled, XCD-chunked (R6 proven) ----------
template<int ACT, bool OF32>
__global__ __launch_bounds__(256) void gemm64_k(
    const u16* __restrict__ A, int lda,
    const u16* __restrict__ Bt, int ldb,
    void* __restrict__ Craw, int ldc,
    const u16* __restrict__ bias, int K)
{
  __shared__ u16 As[128 * 64];   // 16KB, swizzled ch^(r&7)
  __shared__ u16 Bs[128 * 64];   // 16KB, swizzled
  const int blk = blockIdx.x;                   // 768 = 128 mt x 6 nt
  const int wg = (blk & 7) * 96 + (blk >> 3);
  const int mt = (wg / 6) * 128, nt = (wg % 6) * 128;
  const int t = threadIdx.x, wave = t >> 6, lane = t & 63;
  const int wm = (wave >> 1) * 64, wn = (wave & 1) * 64;
  const int lrow = lane & 15, quad = lane >> 4;
  f32x4 acc[4][4] = {};

  for (int k0 = 0; k0 < K; k0 += 64) {
    __syncthreads();
    #pragma unroll
    for (int p = 0; p < 4; ++p) {
      const int slot = wave * 256 + p * 64 + lane;
      const int r = slot >> 3, ch = slot & 7;
      const int chs = ch ^ (r & 7);
      const int lb = (wave * 256 + p * 64) * 8;
      GLDS16(&A[(size_t)(mt + r) * lda + k0 + chs * 8], &As[lb]);
      GLDS16(&Bt[(size_t)(nt + r) * ldb + k0 + chs * 8], &Bs[lb]);
    }
    __syncthreads();

    #pragma unroll
    for (int c = 0; c < 2; ++c) {
      bf16x8 av[4], bv[4];
      #pragma unroll
      for (int i = 0; i < 4; ++i) {
        const int row = wm + i * 16 + lrow;
        av[i] = *(const bf16x8*)&As[row * 64 + (((c * 4 + quad) ^ (row & 7)) * 8)];
      }
      #pragma unroll
      for (int j = 0; j < 4; ++j) {
        const int row = wn + j * 16 + lrow;
        bv[j] = *(const bf16x8*)&Bs[row * 64 + (((c * 4 + quad) ^ (row & 7)) * 8)];
      }
      #pragma unroll
      for (int i = 0; i < 4; ++i)
        #pragma unroll
        for (int j = 0; j < 4; ++j)
          acc[i][j] = __builtin_amdgcn_mfma_f32_16x16x32_bf16(av[i], bv[j], acc[i][j], 0, 0, 0);
    }
  }

  #pragma unroll
  for (int i = 0; i < 4; ++i) {
    #pragma unroll
    for (int j = 0; j < 4; ++j) {
      const int col = nt + wn + j * 16 + lrow;
      const float badd = bias ? bf2f(bias[col]) : 0.0f;
      #pragma unroll
      for (int r = 0; r < 4; ++r) {
        const int row = mt + wm + i * 16 + quad * 4 + r;
        float v = acc[i][j][r] + badd;
        if constexpr (ACT == 1) v = v > 0.0f ? v + 1.0f : __expf(v);
        if constexpr (OF32) ((float*)Craw)[(size_t)row * ldc + col] = v;
        else                ((u16*)Craw)[(size_t)row * ldc + col] = f2bf(v);
      }
    }
  }
}

// ---------------- fused phi_k/vals GEMM + KV-state, double-buffered (R12 proven) ----------
__global__ __launch_bounds__(256) void fkv_k(
    const u16* __restrict__ key_ds,   // [2][32][64][768] bf16
    const u16* __restrict__ WT,       // WkT at +768^2, WvT at +2*768^2
    const u16* __restrict__ bias_c,   // bk at +768, bv at +1536
    u16* __restrict__ sT, float* __restrict__ z)
{
  __shared__ char sm[65536];
  u16* T0 = (u16*)sm;                 // buf b: u16 offset b*16384; tile w: +w*4096
  u16* Pt = (u16*)sm;                 // [64][72] overlay after loop
  u16* Vt = (u16*)(sm + 9216);        // [64][72]
  const int x = blockIdx.x;           // b*12 + n
  const int b = x / 12, n = x % 12;
  const int t = threadIdx.x, wave = t >> 6, lane = t & 63;
  const u16* srcs[4] = {
    key_ds + (size_t)b * 49152,
    WT + 589824 + (size_t)n * 49152,
    key_ds + 1572864 + (size_t)b * 49152,
    WT + 2 * 589824 + (size_t)n * 49152 };
  const int grow = lane >> 3;
  const int gchunk = (lane & 7) ^ (grow & 7);
  const int isV = wave & 1;
  const int wm = (wave >> 1) * 32;
  const int lrow = lane & 15, quad = lane >> 4;
  f32x4 acc[2][4] = {};

  auto stage = [&](int buf, int k0) {   // wave w loads tile w into buffer buf
    const u16* s = srcs[wave];
    char* dtile = sm + buf * 32768 + wave * 8192;   // tile = 64x64 bf16 = 8192 B
    #pragma unroll
    for (int j = 0; j < 8; ++j) {
      const u16* gsrc = s + (size_t)(j * 8 + grow) * 768 + k0 + gchunk * 8;
      GLDS16(gsrc, dtile + j * 1024);
    }
  };

  stage(0, 0);
  __syncthreads();
  int buf = 0;
  for (int ks = 0; ks < 12; ++ks) {
    if (ks < 11) stage(buf ^ 1, (ks + 1) * 64);   // flies during MFMA below
    const u16* Atile = T0 + buf * 16384 + (isV ? 2 : 0) * 4096;
    const u16* Btile = T0 + buf * 16384 + (isV ? 3 : 1) * 4096;
    #pragma unroll
    for (int c = 0; c < 2; ++c) {
      bf16x8 av[2], bv[4];
      #pragma unroll
      for (int i = 0; i < 2; ++i) {
        const int row = wm + i * 16 + lrow;
        av[i] = *(const bf16x8*)&Atile[row * 64 + (((c * 4 + quad) ^ (row & 7)) * 8)];
      }
      #pragma unroll
      for (int j = 0; j < 4; ++j) {
        const int row = j * 16 + lrow;
        bv[j] = *(const bf16x8*)&Btile[row * 64 + (((c * 4 + quad) ^ (row & 7)) * 8)];
      }
      #pragma unroll
      for (int i = 0; i < 2; ++i)
        #pragma unroll
        for (int j = 0; j < 4; ++j)
          acc[i][j] = __builtin_amdgcn_mfma_f32_16x16x32_bf16(av[i], bv[j], acc[i][j], 0, 0, 0);
    }
    __syncthreads();   // drains GLDS(buf^1) + this step's LDS reads
    buf ^= 1;
  }

  const u16* bias = bias_c + (isV ? 1536 : 768) + n * 64;
  u16* Ttile = isV ? Vt : Pt;
  #pragma unroll
  for (int i = 0; i < 2; ++i)
    #pragma unroll
    for (int j = 0; j < 4; ++j) {
      const int col = j * 16 + lrow;
      const float badd = bf2f(bias[col]);
      u16x4 pk4;
      #pragma unroll
      for (int r = 0; r < 4; ++r) {
        float v = acc[i][j][r] + badd;
        if (!isV) v = v > 0.0f ? v + 1.0f : __expf(v);
        pk4[r] = f2bf(v);
      }
      *(u16x4*)&Ttile[col * 72 + wm + i * 16 + quad * 4] = pk4;
    }
  __syncthreads();

  const int wm2 = (wave >> 1) * 32, wn2 = (wave & 1) * 32;
  f32x4 a2[2][2] = {};
  #pragma unroll
  for (int c = 0; c < 2; ++c) {
    bf16x8 av[2], bv[2];
    #pragma unroll
    for (int i = 0; i < 2; ++i)
      av[i] = *(const bf16x8*)&Vt[(wm2 + i * 16 + lrow) * 72 + c * 32 + quad * 8];
    #pragma unroll
    for (int j = 0; j < 2; ++j)
      bv[j] = *(const bf16x8*)&Pt[(wn2 + j * 16 + lrow) * 72 + c * 32 + quad * 8];
    #pragma unroll
    for (int i = 0; i < 2; ++i)
      #pragma unroll
      for (int j = 0; j < 2; ++j)
        a2[i][j] = __builtin_amdgcn_mfma_f32_16x16x32_bf16(av[i], bv[j], a2[i][j], 0, 0, 0);
  }
  u16* sTg = sT + (size_t)x * 4096;
  #pragma unroll
  for (int i = 0; i < 2; ++i)
    #pragma unroll
    for (int j = 0; j < 2; ++j)
      #pragma unroll
      for (int r = 0; r < 4; ++r)
        sTg[(size_t)(wm2 + i * 16 + quad * 4 + r) * 64 + wn2 + j * 16 + lrow] = f2bf(a2[i][j][r]);
  if (t < 64) {
    float zz = 0.f;
    #pragma unroll
    for (int g = 0; g < 8; ++g) {
      u16x8 p = *(const u16x8*)&Pt[t * 72 + g * 8];
      #pragma unroll
      for (int e = 0; e < 8; ++e) zz += bf2f(p[e]);
    }
    z[(size_t)x * 64 + t] = zz;
  }
}

// ---------------- a_v = (phi_q @ s) / (phi_q . z + eps), fused qz, in-place (R6) --------
__global__ __launch_bounds__(256) void attn_av_k(
    u16* __restrict__ phi_q, const u16* __restrict__ sT, const float* __restrict__ zbuf)
{
  __shared__ u16 As[64 * 72];
  __shared__ u16 Bs[64 * 72];
  __shared__ float zv[64];
  __shared__ float zpart[4][64];
  __shared__ float zq[64];
  const int x = blockIdx.x, y = blockIdx.y;
  const int b = y / 12, n = y % 12;
  const int t = threadIdx.x;
  u16* Abase = phi_q + (size_t)b * 512 * 768 + (size_t)x * 64 * 768 + n * 64;
  const u16* Bbase = sT + (size_t)y * 4096;
  if (t < 64) zv[t] = zbuf[(size_t)y * 64 + t];
  #pragma unroll
  for (int p = 0; p < 2; ++p) {
    int v = t + p * 256;
    int r = v >> 3, c = (v & 7) * 8;
    *(u16x8*)&As[r * 72 + c] = *(const u16x8*)&Abase[(size_t)r * 768 + c];
    *(u16x8*)&Bs[r * 72 + c] = *(const u16x8*)&Bbase[r * 64 + c];
  }
  __syncthreads();
  {
    int r = t & 63, seg = t >> 6;
    float s = 0.f;
    #pragma unroll
    for (int j = 0; j < 16; ++j) s += bf2f(As[r * 72 + seg * 16 + j]) * zv[seg * 16 + j];
    zpart[seg][r] = s;
  }
  __syncthreads();
  if (t < 64) {
    float s = zpart[0][t] + zpart[1][t] + zpart[2][t] + zpart[3][t];
    zq[t] = 1.0f / (s + 1e-6f);
  }
  const int wave = t >> 6, lane = t & 63;
  const int wm = (wave >> 1) * 32, wn = (wave & 1) * 32;
  const int lrow = lane & 15, quad = lane >> 4;
  f32x4 acc[2][2] = {};
  #pragma unroll
  for (int c = 0; c < 2; ++c) {
    bf16x8 av[2], bv[2];
    #pragma unroll
    for (int i = 0; i < 2; ++i) av[i] = *(const bf16x8*)&As[(wm + i * 16 + lrow) * 72 + c * 32 + quad * 8];
    #pragma unroll
    for (int j = 0; j < 2; ++j) bv[j] = *(const bf16x8*)&Bs[(wn + j * 16 + lrow) * 72 + c * 32 + quad * 8];
    #pragma unroll
    for (int i = 0; i < 2; ++i)
      #pragma unroll
      for (int j = 0; j < 2; ++j)
        acc[i][j] = __builtin_amdgcn_mfma_f32_16x16x32_bf16(av[i], bv[j], acc[i][j], 0, 0, 0);
  }
  __syncthreads();
  #pragma unroll
  for (int i = 0; i < 2; ++i)
    #pragma unroll
    for (int j = 0; j < 2; ++j) {
      const int col = wn + j * 16 + lrow;
      #pragma unroll
      for (int r = 0; r < 4; ++r) {
        const int row = wm + i * 16 + quad * 4 + r;
        Abase[(size_t)row * 768 + col] = f2bf(acc[i][j][r] * zq[row]);
      }
    }
}

__global__ void tagfill_k(float* out, float val, int n) {
  int i = blockIdx.x * 256 + threadIdx.x;
  if (i < n) out[i] = val;
}

extern "C" void kernel_launch(void* const* d_in, const int* in_sizes, int n_in,
                              void* d_out, int out_size, void* d_ws, size_t ws_size,
                              hipStream_t stream) {
  (void)out_size;
  float* out = (float*)d_out;

  int o;
  if (n_in >= 14 && in_sizes[3] == 1) o = 4;
  else if (n_in == 13) o = 3;
  else { tagfill_k<<<4, 256, 0, stream>>>(out, 77.0f, 1024); return; }
  if (in_sizes[0] != 12582912 || in_sizes[o + 0] != 32768 || in_sizes[o + 2] != 589824) {
    tagfill_k<<<4, 256, 0, stream>>>(out, 88.0f, 1024); return;
  }

  const float* query = (const float*)d_in[0];
  const float* key   = (const float*)d_in[1];
  const float* value = (const float*)d_in[2];
  const float* W_kds = (const float*)d_in[o + 0];
  const float* W_vds = (const float*)d_in[o + 1];
  const float* Wq   = (const float*)d_in[o + 2];
  const float* bq   = (const float*)d_in[o + 3];
  const float* Wk   = (const float*)d_in[o + 4];
  const float* bk   = (const float*)d_in[o + 5];
  const float* Wv   = (const float*)d_in[o + 6];
  const float* bv   = (const float*)d_in[o + 7];
  const float* Wout = (const float*)d_in[o + 8];
  const float* bout = (const float*)d_in[o + 9];

  const size_t NEED = 61478912;
  if (ws_size < NEED) { tagfill_k<<<4, 256, 0, stream>>>(out, 123.0f, 1024); return; }

  char* base = (char*)d_ws;
  u16*   WT     = (u16*)base;                         // 4,718,592
  char*  Breg   = base + 4718592;                     // 25,165,824 region
  u16*   q_bf   = (u16*)Breg;                         // dies after phi_q GEMM
  u16*   sT     = (u16*)Breg;                         // then sT (over dead q_bf)
  float* zbuf   = (float*)(Breg + 3145728);
  u16*   phi_q  = (u16*)(base + 29884416);            // 25,165,824
  u16*   Wds_c  = (u16*)(base + 55050240);            // 131,072
  u16*   bias_c = (u16*)(base + 55181312);            // 6,144
  u16*   key_ds = (u16*)(base + 55187456);            // 6,291,456
  u16* a_v = phi_q;
  u16* WqT   = WT;
  u16* WoutT = WT + 3 * 768 * 768;
  u16* bq_c = bias_c, *bout_c = bias_c + 2304;

  // 1. prep: W transposes + query cvt + Wds/bias cvt
  prep_k<<<6988, 256, 0, stream>>>(Wq, Wk, Wv, Wout, query, W_kds, W_vds,
                                   bq, bk, bv, bout, WT, q_bf, Wds_c, bias_c);

  // 2. phi_q = elu(q_bf @ WqT + bq) + 1  (bf16 A, GLDS, BK=64)
  gemm64_k<1, false><<<768, 256, 0, stream>>>(
      q_bf, 768, WqT, 768, phi_q, 768, bq_c, 768);

  // 3. downsample v7 (coalesced GLDS rows + LDS-side transpose)
  ds_k<<<dim3(12, 64), 256, 0, stream>>>(Wds_c, key, value, key_ds);

  // 4. fused phi_k/vals + KV state, double-buffered (sT/zbuf overwrite dead q_bf)
  fkv_k<<<384, 256, 0, stream>>>(key_ds, WT, bias_c, sT, zbuf);

  // 5. a_v = (phi_q @ s) * 1/(phi_q.z+eps), fused qz, in-place
  attn_av_k<<<dim3(8, 384), 256, 0, stream>>>(phi_q, sT, zbuf);

  // 6. out = a_v @ Wout + bout (fp32 C, XCD-swizzled)
  gemm64_k<0, true><<<768, 256, 0, stream>>>(
      a_v, 768, WoutT, 768, out, 768, bout_c, 768);
}

// Round 14
// 290.099 us; speedup vs baseline: 1.1020x; 1.0107x over previous
//
#include <hip/hip_runtime.h>

typedef unsigned short u16;
typedef u16 u16x4 __attribute__((ext_vector_type(4)));
typedef u16 u16x8 __attribute__((ext_vector_type(8)));
typedef __bf16 bf16;
typedef bf16 bf16x8 __attribute__((ext_vector_type(8)));
typedef float f32x4 __attribute__((ext_vector_type(4)));

__device__ __forceinline__ float bf2f(u16 v) {
  union { unsigned u; float f; } x; x.u = ((unsigned)v) << 16; return x.f;
}
__device__ __forceinline__ u16 f2bf(float f) {
  union { float f; unsigned u; } x; x.f = f;
  unsigned u = x.u;
  u += 0x7fffu + ((u >> 16) & 1u);   // RNE
  return (u16)(u >> 16);
}
// hw packed f32->bf16 (RNE), 2 values / instr (no builtin on gfx950, m240)
__device__ __forceinline__ unsigned cvt2bf(float lo, float hi) {
  unsigned r;
  asm("v_cvt_pk_bf16_f32 %0, %1, %2" : "=v"(r) : "v"(lo), "v"(hi));
  return r;
}

// lgkm-only barrier: LDS drained, global loads stay in flight
__device__ __forceinline__ void bar_lgkm() {
  asm volatile("s_waitcnt lgkmcnt(0)" ::: "memory");
  __builtin_amdgcn_s_barrier();
}

// async global->LDS, 16B per lane; LDS base wave-uniform, global source per-lane (m173)
#define GLDS16(g, l) __builtin_amdgcn_global_load_lds( \
    (const __attribute__((address_space(1))) unsigned int*)(const void*)(g), \
    (__attribute__((address_space(3))) unsigned int*)(void*)(l), 16, 0, 0)

// ---------------- prep: 4 weight transposes + query cvt + small cvts (R0/R8 proven) -----
__global__ __launch_bounds__(256) void prep_k(
    const float* __restrict__ Wq, const float* __restrict__ Wk,
    const float* __restrict__ Wv, const float* __restrict__ Wout,
    const float* __restrict__ query,
    const float* __restrict__ wkds, const float* __restrict__ wvds,
    const float* __restrict__ b0, const float* __restrict__ b1,
    const float* __restrict__ b2, const float* __restrict__ b3,
    u16* __restrict__ WT, u16* __restrict__ q_bf,
    u16* __restrict__ dstW, u16* __restrict__ dstB)
{
  __shared__ u16 T[64][72];
  const int blk = blockIdx.x;
  const int t = threadIdx.x;
  if (blk < 576) {
    const int bz = blk / 144, rr = blk % 144;
    const int r0 = (rr / 12) * 64, c0 = (rr % 12) * 64;
    const float* W = (bz == 0) ? Wq : (bz == 1) ? Wk : (bz == 2) ? Wv : Wout;
    u16* O = WT + (size_t)bz * 768 * 768;
    #pragma unroll
    for (int p = 0; p < 2; ++p) {
      int v = t + p * 256;
      int r = v / 8, c = (v % 8) * 8;
      f32x4 x0 = *(const f32x4*)&W[(size_t)(r0 + r) * 768 + c0 + c];
      f32x4 x1 = *(const f32x4*)&W[(size_t)(r0 + r) * 768 + c0 + c + 4];
      #pragma unroll
      for (int i = 0; i < 4; ++i) { T[r][c + i] = f2bf(x0[i]); T[r][c + 4 + i] = f2bf(x1[i]); }
    }
    __syncthreads();
    #pragma unroll
    for (int p = 0; p < 2; ++p) {
      int v = t + p * 256;
      int r = v / 8, c = (v % 8) * 8;
      u16x8 tv;
      #pragma unroll
      for (int i = 0; i < 8; ++i) tv[i] = T[c + i][r];
      *(u16x8*)&O[(size_t)(c0 + r) * 768 + r0 + c] = tv;
    }
  } else if (blk < 6720) {
    const size_t i = (size_t)(blk - 576) * 256 + t;   // 6144*256 slots, *8 = 12582912
    f32x4 a = *(const f32x4*)&query[i * 8];
    f32x4 b = *(const f32x4*)&query[i * 8 + 4];
    u16x8 w;
    #pragma unroll
    for (int j = 0; j < 4; ++j) { w[j] = f2bf(a[j]); w[4 + j] = f2bf(b[j]); }
    *(u16x8*)&q_bf[i * 8] = w;
  } else {
    const int i = (blk - 6720) * 256 + t;   // 268*256 = 68608 = 65536 + 3072
    if (i < 32768)      dstW[i] = f2bf(wkds[i]);
    else if (i < 65536) dstW[i] = f2bf(wvds[i - 32768]);
    else {
      int j = i - 65536, s = j / 768, si = j % 768;
      const float* src = (s == 0) ? b0 : (s == 1) ? b1 : (s == 2) ? b2 : b3;
      dstB[j] = f2bf(src[si]);
    }
  }
}

// ---------------- downsample v8: coalesced GLDS + REGISTER 4x4 transpose + k-major LDS ----
// v7 was LDS-pipe-bound (64 scalar b32 reads/thread/chunk). v8: each thread transposes
// one 4x4 fp32 block in REGISTERS (4x b128 read, cvt_pk, 2x b32-pair write per n) into a
// k-major bf16 buffer Kb[n][72-pad]; compute reads b128 fragments (conflict-free via pad).
// LDS ops/thread/chunk: 64 scalar -> ~20 mostly-wide. Global stays coalesced (v7 staging).
__global__ __launch_bounds__(256) void ds_k(
    const u16* __restrict__ Wds,      // bf16 [2][64][512]
    const float* __restrict__ key, const float* __restrict__ value,
    u16* __restrict__ key_ds)         // [2][32][64][768] (key_ds ++ val_ds contiguous)
{
  __shared__ float Sg[2][64 * 64];   // 16KB each: fp32 chunk, v7 staging layout
  __shared__ u16  Kb[2][64 * 72];    // 9KB each: bf16 k-major [n][72]
  const int pair = blockIdx.y >> 5, b = blockIdx.y & 31;
  const float* src = (pair ? value : key) + (size_t)b * 512 * 768;
  const u16* W = Wds + pair * 32768;
  u16* dst = key_ds + (size_t)pair * 1572864 + (size_t)b * 49152;
  const int nt = blockIdx.x * 64;
  const int t = threadIdx.x, wave = t >> 6, lane = t & 63;
  const int wm = wave * 16;                    // 4 waves x 16 kds-rows
  const int lrow = lane & 15, quad = lane >> 4;
  const int k4 = t >> 4, n4 = t & 15;          // transpose: 4x4 block (k4*4.., n4*4..)

  // preload ALL W fragments for this wave's 16 rows (L2-hot, zero loop traffic)
  bf16x8 wreg[16];
  #pragma unroll
  for (int c = 0; c < 16; ++c)
    wreg[c] = *(const bf16x8*)&W[(size_t)(wm + lrow) * 512 + c * 32 + quad * 8];

  // stage one 64k x 64n fp32 chunk (v7 layout: LDS pos c holds global chunk c^(g&15))
  auto stage = [&](int bufi, int kb) {
    #pragma unroll
    for (int p = 0; p < 4; ++p) {
      const int g = wave * 4 + p;
      const int row = kb + g * 4 + (lane >> 4);
      const int ch = (lane & 15) ^ (g & 15);
      GLDS16(&src[(size_t)row * 768 + nt + ch * 4], (char*)&Sg[bufi][0] + g * 1024);
    }
  };
  // register 4x4 transpose: Sg[bufi] -> Kb[bufi] (k-major, padded 72)
  auto transp = [&](int bufi) {
    f32x4 r[4];
    #pragma unroll
    for (int i = 0; i < 4; ++i) {
      const int k = k4 * 4 + i;
      r[i] = *(const f32x4*)&Sg[bufi][k * 64 + ((n4 ^ (k4 & 15)) & 15) * 4];
    }
    #pragma unroll
    for (int nn = 0; nn < 4; ++nn) {
      unsigned* p2 = (unsigned*)&Kb[bufi][(n4 * 4 + nn) * 72 + k4 * 4];
      p2[0] = cvt2bf(r[0][nn], r[1][nn]);   // k4*4+0, +1
      p2[1] = cvt2bf(r[2][nn], r[3][nn]);   // k4*4+2, +3
    }
  };

  f32x4 acc[4] = {};
  stage(0, 0);
  __syncthreads();                 // Sg[0] ready (vmcnt drained)
  stage(1, 64);                    // chunk 1 in flight
  transp(0);
  bar_lgkm();                      // Kb[0] visible; GLDS(1) still flying
  int cur = 0;
  #pragma unroll
  for (int cc = 0; cc < 8; ++cc) {
    // compute chunk cc from Kb[cur]
    #pragma unroll
    for (int kc = 0; kc < 2; ++kc) {
      bf16x8 bv[4];
      #pragma unroll
      for (int j = 0; j < 4; ++j) {
        const int n = j * 16 + lrow;
        bv[j] = *(const bf16x8*)&Kb[cur][n * 72 + kc * 32 + quad * 8];
      }
      #pragma unroll
      for (int j = 0; j < 4; ++j)
        acc[j] = __builtin_amdgcn_mfma_f32_16x16x32_bf16(wreg[cc * 2 + kc], bv[j], acc[j], 0, 0, 0);
    }
    if (cc < 7) {
      __syncthreads();                       // drains GLDS(cc+1) -> Sg[cur^1]
      if (cc < 6) stage(cur, (cc + 2) * 64); // Sg[cur] free (transposed last iter)
      transp(cur ^ 1);                       // Sg[cur^1] -> Kb[cur^1]
      bar_lgkm();                            // Kb[cur^1] visible; GLDS flying
      cur ^= 1;
    }
  }

  #pragma unroll
  for (int j = 0; j < 4; ++j) {
    const int col = nt + j * 16 + lrow;
    #pragma unroll
    for (int r = 0; r < 4; ++r) {
      const int row = wm + quad * 4 + r;
      dst[(size_t)row * 768 + col] = f2bf(acc[j][r]);
    }
  }
}

// ---------------- bf16 GEMM, BK=64, GLDS, swizzled, XCD-chunked (R6 proven) ----------
template<int ACT, bool OF32>
__global__ __launch_bounds__(256) void gemm64_k(
    const u16* __restrict__ A, int lda,
    const u16* __restrict__ Bt, int ldb,
    void* __restrict__ Craw, int ldc,
    const u16* __restrict__ bias, int K)
{
  __shared__ u16 As[128 * 64];   // 16KB, swizzled ch^(r&7)
  __shared__ u16 Bs[128 * 64];   // 16KB, swizzled
  const int blk = blockIdx.x;                   // 768 = 128 mt x 6 nt
  const int wg = (blk & 7) * 96 + (blk >> 3);
  const int mt = (wg / 6) * 128, nt = (wg % 6) * 128;
  const int t = threadIdx.x, wave = t >> 6, lane = t & 63;
  const int wm = (wave >> 1) * 64, wn = (wave & 1) * 64;
  const int lrow = lane & 15, quad = lane >> 4;
  f32x4 acc[4][4] = {};

  for (int k0 = 0; k0 < K; k0 += 64) {
    __syncthreads();
    #pragma unroll
    for (int p = 0; p < 4; ++p) {
      const int slot = wave * 256 + p * 64 + lane;
      const int r = slot >> 3, ch = slot & 7;
      const int chs = ch ^ (r & 7);
      const int lb = (wave * 256 + p * 64) * 8;
      GLDS16(&A[(size_t)(mt + r) * lda + k0 + chs * 8], &As[lb]);
      GLDS16(&Bt[(size_t)(nt + r) * ldb + k0 + chs * 8], &Bs[lb]);
    }
    __syncthreads();

    #pragma unroll
    for (int c = 0; c < 2; ++c) {
      bf16x8 av[4], bv[4];
      #pragma unroll
      for (int i = 0; i < 4; ++i) {
        const int row = wm + i * 16 + lrow;
        av[i] = *(const bf16x8*)&As[row * 64 + (((c * 4 + quad) ^ (row & 7)) * 8)];
      }
      #pragma unroll
      for (int j = 0; j < 4; ++j) {
        const int row = wn + j * 16 + lrow;
        bv[j] = *(const bf16x8*)&Bs[row * 64 + (((c * 4 + quad) ^ (row & 7)) * 8)];
      }
      #pragma unroll
      for (int i = 0; i < 4; ++i)
        #pragma unroll
        for (int j = 0; j < 4; ++j)
          acc[i][j] = __builtin_amdgcn_mfma_f32_16x16x32_bf16(av[i], bv[j], acc[i][j], 0, 0, 0);
    }
  }

  #pragma unroll
  for (int i = 0; i < 4; ++i) {
    #pragma unroll
    for (int j = 0; j < 4; ++j) {
      const int col = nt + wn + j * 16 + lrow;
      const float badd = bias ? bf2f(bias[col]) : 0.0f;
      #pragma unroll
      for (int r = 0; r < 4; ++r) {
        const int row = mt + wm + i * 16 + quad * 4 + r;
        float v = acc[i][j][r] + badd;
        if constexpr (ACT == 1) v = v > 0.0f ? v + 1.0f : __expf(v);
        if constexpr (OF32) ((float*)Craw)[(size_t)row * ldc + col] = v;
        else                ((u16*)Craw)[(size_t)row * ldc + col] = f2bf(v);
      }
    }
  }
}

// ---------------- fused phi_k/vals GEMM + KV-state, double-buffered (R12 proven) ----------
__global__ __launch_bounds__(256) void fkv_k(
    const u16* __restrict__ key_ds,   // [2][32][64][768] bf16
    const u16* __restrict__ WT,       // WkT at +768^2, WvT at +2*768^2
    const u16* __restrict__ bias_c,   // bk at +768, bv at +1536
    u16* __restrict__ sT, float* __restrict__ z)
{
  __shared__ char sm[65536];
  u16* T0 = (u16*)sm;                 // buf b: u16 offset b*16384; tile w: +w*4096
  u16* Pt = (u16*)sm;                 // [64][72] overlay after loop
  u16* Vt = (u16*)(sm + 9216);        // [64][72]
  const int x = blockIdx.x;           // b*12 + n
  const int b = x / 12, n = x % 12;
  const int t = threadIdx.x, wave = t >> 6, lane = t & 63;
  const u16* srcs[4] = {
    key_ds + (size_t)b * 49152,
    WT + 589824 + (size_t)n * 49152,
    key_ds + 1572864 + (size_t)b * 49152,
    WT + 2 * 589824 + (size_t)n * 49152 };
  const int grow = lane >> 3;
  const int gchunk = (lane & 7) ^ (grow & 7);
  const int isV = wave & 1;
  const int wm = (wave >> 1) * 32;
  const int lrow = lane & 15, quad = lane >> 4;
  f32x4 acc[2][4] = {};

  auto stage = [&](int buf, int k0) {   // wave w loads tile w into buffer buf
    const u16* s = srcs[wave];
    char* dtile = sm + buf * 32768 + wave * 8192;   // tile = 64x64 bf16 = 8192 B
    #pragma unroll
    for (int j = 0; j < 8; ++j) {
      const u16* gsrc = s + (size_t)(j * 8 + grow) * 768 + k0 + gchunk * 8;
      GLDS16(gsrc, dtile + j * 1024);
    }
  };

  stage(0, 0);
  __syncthreads();
  int buf = 0;
  for (int ks = 0; ks < 12; ++ks) {
    if (ks < 11) stage(buf ^ 1, (ks + 1) * 64);   // flies during MFMA below
    const u16* Atile = T0 + buf * 16384 + (isV ? 2 : 0) * 4096;
    const u16* Btile = T0 + buf * 16384 + (isV ? 3 : 1) * 4096;
    #pragma unroll
    for (int c = 0; c < 2; ++c) {
      bf16x8 av[2], bv[4];
      #pragma unroll
      for (int i = 0; i < 2; ++i) {
        const int row = wm + i * 16 + lrow;
        av[i] = *(const bf16x8*)&Atile[row * 64 + (((c * 4 + quad) ^ (row & 7)) * 8)];
      }
      #pragma unroll
      for (int j = 0; j < 4; ++j) {
        const int row = j * 16 + lrow;
        bv[j] = *(const bf16x8*)&Btile[row * 64 + (((c * 4 + quad) ^ (row & 7)) * 8)];
      }
      #pragma unroll
      for (int i = 0; i < 2; ++i)
        #pragma unroll
        for (int j = 0; j < 4; ++j)
          acc[i][j] = __builtin_amdgcn_mfma_f32_16x16x32_bf16(av[i], bv[j], acc[i][j], 0, 0, 0);
    }
    __syncthreads();   // drains GLDS(buf^1) + this step's LDS reads
    buf ^= 1;
  }

  const u16* bias = bias_c + (isV ? 1536 : 768) + n * 64;
  u16* Ttile = isV ? Vt : Pt;
  #pragma unroll
  for (int i = 0; i < 2; ++i)
    #pragma unroll
    for (int j = 0; j < 4; ++j) {
      const int col = j * 16 + lrow;
      const float badd = bf2f(bias[col]);
      u16x4 pk4;
      #pragma unroll
      for (int r = 0; r < 4; ++r) {
        float v = acc[i][j][r] + badd;
        if (!isV) v = v > 0.0f ? v + 1.0f : __expf(v);
        pk4[r] = f2bf(v);
      }
      *(u16x4*)&Ttile[col * 72 + wm + i * 16 + quad * 4] = pk4;
    }
  __syncthreads();

  const int wm2 = (wave >> 1) * 32, wn2 = (wave & 1) * 32;
  f32x4 a2[2][2] = {};
  #pragma unroll
  for (int c = 0; c < 2; ++c) {
    bf16x8 av[2], bv[2];
    #pragma unroll
    for (int i = 0; i < 2; ++i)
      av[i] = *(const bf16x8*)&Vt[(wm2 + i * 16 + lrow) * 72 + c * 32 + quad * 8];
    #pragma unroll
    for (int j = 0; j < 2; ++j)
      bv[j] = *(const bf16x8*)&Pt[(wn2 + j * 16 + lrow) * 72 + c * 32 + quad * 8];
    #pragma unroll
    for (int i = 0; i < 2; ++i)
      #pragma unroll
      for (int j = 0; j < 2; ++j)
        a2[i][j] = __builtin_amdgcn_mfma_f32_16x16x32_bf16(av[i], bv[j], a2[i][j], 0, 0, 0);
  }
  u16* sTg = sT + (size_t)x * 4096;
  #pragma unroll
  for (int i = 0; i < 2; ++i)
    #pragma unroll
    for (int j = 0; j < 2; ++j)
      #pragma unroll
      for (int r = 0; r < 4; ++r)
        sTg[(size_t)(wm2 + i * 16 + quad * 4 + r) * 64 + wn2 + j * 16 + lrow] = f2bf(a2[i][j][r]);
  if (t < 64) {
    float zz = 0.f;
    #pragma unroll
    for (int g = 0; g < 8; ++g) {
      u16x8 p = *(const u16x8*)&Pt[t * 72 + g * 8];
      #pragma unroll
      for (int e = 0; e < 8; ++e) zz += bf2f(p[e]);
    }
    z[(size_t)x * 64 + t] = zz;
  }
}

// ---------------- a_v = (phi_q @ s) / (phi_q . z + eps), fused qz, in-place (R6) --------
__global__ __launch_bounds__(256) void attn_av_k(
    u16* __restrict__ phi_q, const u16* __restrict__ sT, const float* __restrict__ zbuf)
{
  __shared__ u16 As[64 * 72];
  __shared__ u16 Bs[64 * 72];
  __shared__ float zv[64];
  __shared__ float zpart[4][64];
  __shared__ float zq[64];
  const int x = blockIdx.x, y = blockIdx.y;
  const int b = y / 12, n = y % 12;
  const int t = threadIdx.x;
  u16* Abase = phi_q + (size_t)b * 512 * 768 + (size_t)x * 64 * 768 + n * 64;
  const u16* Bbase = sT + (size_t)y * 4096;
  if (t < 64) zv[t] = zbuf[(size_t)y * 64 + t];
  #pragma unroll
  for (int p = 0; p < 2; ++p) {
    int v = t + p * 256;
    int r = v >> 3, c = (v & 7) * 8;
    *(u16x8*)&As[r * 72 + c] = *(const u16x8*)&Abase[(size_t)r * 768 + c];
    *(u16x8*)&Bs[r * 72 + c] = *(const u16x8*)&Bbase[r * 64 + c];
  }
  __syncthreads();
  {
    int r = t & 63, seg = t >> 6;
    float s = 0.f;
    #pragma unroll
    for (int j = 0; j < 16; ++j) s += bf2f(As[r * 72 + seg * 16 + j]) * zv[seg * 16 + j];
    zpart[seg][r] = s;
  }
  __syncthreads();
  if (t < 64) {
    float s = zpart[0][t] + zpart[1][t] + zpart[2][t] + zpart[3][t];
    zq[t] = 1.0f / (s + 1e-6f);
  }
  const int wave = t >> 6, lane = t & 63;
  const int wm = (wave >> 1) * 32, wn = (wave & 1) * 32;
  const int lrow = lane & 15, quad = lane >> 4;
  f32x4 acc[2][2] = {};
  #pragma unroll
  for (int c = 0; c < 2; ++c) {
    bf16x8 av[2], bv[2];
    #pragma unroll
    for (int i = 0; i < 2; ++i) av[i] = *(const bf16x8*)&As[(wm + i * 16 + lrow) * 72 + c * 32 + quad * 8];
    #pragma unroll
    for (int j = 0; j < 2; ++j) bv[j] = *(const bf16x8*)&Bs[(wn + j * 16 + lrow) * 72 + c * 32 + quad * 8];
    #pragma unroll
    for (int i = 0; i < 2; ++i)
      #pragma unroll
      for (int j = 0; j < 2; ++j)
        acc[i][j] = __builtin_amdgcn_mfma_f32_16x16x32_bf16(av[i], bv[j], acc[i][j], 0, 0, 0);
  }
  __syncthreads();
  #pragma unroll
  for (int i = 0; i < 2; ++i)
    #pragma unroll
    for (int j = 0; j < 2; ++j) {
      const int col = wn + j * 16 + lrow;
      #pragma unroll
      for (int r = 0; r < 4; ++r) {
        const int row = wm + i * 16 + quad * 4 + r;
        Abase[(size_t)row * 768 + col] = f2bf(acc[i][j][r] * zq[row]);
      }
    }
}

__global__ void tagfill_k(float* out, float val, int n) {
  int i = blockIdx.x * 256 + threadIdx.x;
  if (i < n) out[i] = val;
}

extern "C" void kernel_launch(void* const* d_in, const int* in_sizes, int n_in,
                              void* d_out, int out_size, void* d_ws, size_t ws_size,
                              hipStream_t stream) {
  (void)out_size;
  float* out = (float*)d_out;

  int o;
  if (n_in >= 14 && in_sizes[3] == 1) o = 4;
  else if (n_in == 13) o = 3;
  else { tagfill_k<<<4, 256, 0, stream>>>(out, 77.0f, 1024); return; }
  if (in_sizes[0] != 12582912 || in_sizes[o + 0] != 32768 || in_sizes[o + 2] != 589824) {
    tagfill_k<<<4, 256, 0, stream>>>(out, 88.0f, 1024); return;
  }

  const float* query = (const float*)d_in[0];
  const float* key   = (const float*)d_in[1];
  const float* value = (const float*)d_in[2];
  const float* W_kds = (const float*)d_in[o + 0];
  const float* W_vds = (const float*)d_in[o + 1];
  const float* Wq   = (const float*)d_in[o + 2];
  const float* bq   = (const float*)d_in[o + 3];
  const float* Wk   = (const float*)d_in[o + 4];
  const float* bk   = (const float*)d_in[o + 5];
  const float* Wv   = (const float*)d_in[o + 6];
  const float* bv   = (const float*)d_in[o + 7];
  const float* Wout = (const float*)d_in[o + 8];
  const float* bout = (const float*)d_in[o + 9];

  const size_t NEED = 61478912;
  if (ws_size < NEED) { tagfill_k<<<4, 256, 0, stream>>>(out, 123.0f, 1024); return; }

  char* base = (char*)d_ws;
  u16*   WT     = (u16*)base;                         // 4,718,592
  char*  Breg   = base + 4718592;                     // 25,165,824 region
  u16*   q_bf   = (u16*)Breg;                         // dies after phi_q GEMM
  u16*   sT     = (u16*)Breg;                         // then sT (over dead q_bf)
  float* zbuf   = (float*)(Breg + 3145728);
  u16*   phi_q  = (u16*)(base + 29884416);            // 25,165,824
  u16*   Wds_c  = (u16*)(base + 55050240);            // 131,072
  u16*   bias_c = (u16*)(base + 55181312);            // 6,144
  u16*   key_ds = (u16*)(base + 55187456);            // 6,291,456
  u16* a_v = phi_q;
  u16* WqT   = WT;
  u16* WoutT = WT + 3 * 768 * 768;
  u16* bq_c = bias_c, *bout_c = bias_c + 2304;

  // 1. prep: W transposes + query cvt + Wds/bias cvt
  prep_k<<<6988, 256, 0, stream>>>(Wq, Wk, Wv, Wout, query, W_kds, W_vds,
                                   bq, bk, bv, bout, WT, q_bf, Wds_c, bias_c);

  // 2. phi_q = elu(q_bf @ WqT + bq) + 1  (bf16 A, GLDS, BK=64)
  gemm64_k<1, false><<<768, 256, 0, stream>>>(
      q_bf, 768, WqT, 768, phi_q, 768, bq_c, 768);

  // 3. downsample v8 (coalesced GLDS + register transpose + k-major LDS)
  ds_k<<<dim3(12, 64), 256, 0, stream>>>(Wds_c, key, value, key_ds);

  // 4. fused phi_k/vals + KV state, double-buffered (sT/zbuf overwrite dead q_bf)
  fkv_k<<<384, 256, 0, stream>>>(key_ds, WT, bias_c, sT, zbuf);

  // 5. a_v = (phi_q @ s) * 1/(phi_q.z+eps), fused qz, in-place
  attn_av_k<<<dim3(8, 384), 256, 0, stream>>>(phi_q, sT, zbuf);

  // 6. out = a_v @ Wout + bout (fp32 C, XCD-swizzled)
  gemm64_k<0, true><<<768, 256, 0, stream>>>(
      a_v, 768, WoutT, 768, out, 768, bout_c, 768);
}